// Round 12
// baseline (707.287 us; speedup 1.0000x reference)
//
#include <hip/hip_runtime.h>

#define N_RAYS 16384
#define NSAMP  96
#define GD 128
#define GH 128
#define GW 128
#define C_IN  32
#define C_HID 32
#define C_OUT 16
#define M_PTS (N_RAYS * NSAMP)       // 1,572,864 (divisible by 256)
#define TPA 16                        // tiles per axis (128/8)
#define NTILES (TPA*TPA*TPA)          // 4096
#define TW 8                          // tile width (voxels)
#define TVOX (TW*TW*TW)               // 512 voxels per tile
#define CHUNK 256                     // entries staged per K4 inner pass

__device__ __forceinline__ int clampi(int v, int hi) { return min(max(v, 0), hi); }

struct TileSpan { int txa, txb, tya, tyb, tza, tzb; };
__device__ __forceinline__ TileSpan tile_span(int X, int Y, int Z) {
    TileSpan s;
    s.txa = clampi(X,   GW-1) >> 3;  s.txb = clampi(X+1, GW-1) >> 3;
    s.tya = clampi(Y,   GH-1) >> 3;  s.tyb = clampi(Y+1, GH-1) >> 3;
    s.tza = clampi(Z,   GD-1) >> 3;  s.tzb = clampi(Z+1, GD-1) >> 3;
    return s;
}

// ============================================================================
// K1 (LITE): positions + key + per-tile histogram only.
// ============================================================================
__global__ __launch_bounds__(256) void k1_pos(
    const float* __restrict__ origins, const float* __restrict__ dirs,
    const float* __restrict__ nearv,   const float* __restrict__ farv,
    float4* __restrict__ pf, unsigned* __restrict__ counts)
{
    __shared__ unsigned lcnt[NTILES];
    for (int i = threadIdx.x; i < NTILES; i += 256) lcnt[i] = 0;
    __syncthreads();

    int pid = blockIdx.x * 256 + threadIdx.x;
    int ray = pid / NSAMP;
    int s   = pid - ray * NSAMP;

    float nr = nearv[ray], fr = farv[ray];
    float t  = nr + (fr - nr) * ((float)s * (1.0f / (NSAMP - 1)));
    float px = fmaf(t, dirs[ray*3+0], origins[ray*3+0]);
    float py = fmaf(t, dirs[ray*3+1], origins[ray*3+1]);
    float pz = fmaf(t, dirs[ray*3+2], origins[ray*3+2]);

    float cx = ((px + 1.0f) * (float)GW - 1.0f) * 0.5f;
    float cy = ((py + 1.0f) * (float)GH - 1.0f) * 0.5f;
    float cz = ((pz + 1.0f) * (float)GD - 1.0f) * 0.5f;
    float fxf = floorf(cx), fyf = floorf(cy), fzf = floorf(cz);
    float fx = cx - fxf, fy = cy - fyf, fz = cz - fzf;
    int X = (int)fxf, Y = (int)fyf, Z = (int)fzf;

    unsigned key = ((unsigned)(X + 256) & 511u)
                 | (((unsigned)(Y + 256) & 511u) << 9)
                 | (((unsigned)(Z + 256) & 511u) << 18);
    pf[pid] = make_float4(fx, fy, fz, __uint_as_float(key));

    TileSpan ts = tile_span(X, Y, Z);
    #pragma unroll
    for (int ez = 0; ez < 2; ++ez) {
        if (ez && ts.tzb == ts.tza) continue;
        #pragma unroll
        for (int ey = 0; ey < 2; ++ey) {
            if (ey && ts.tyb == ts.tya) continue;
            #pragma unroll
            for (int ex = 0; ex < 2; ++ex) {
                if (ex && ts.txb == ts.txa) continue;
                int tt = ((ts.tza + ez) * TPA + (ts.tya + ey)) * TPA + (ts.txa + ex);
                atomicAdd(&lcnt[tt], 1u);
            }
        }
    }
    __syncthreads();
    for (int i = threadIdx.x; i < NTILES; i += 256)
        if (lcnt[i]) atomicAdd(&counts[i], lcnt[i]);
}

// ============================================================================
// K2: exclusive scan + heavy-first tile schedule.
// ============================================================================
__global__ __launch_bounds__(256) void k2_scan(
    const unsigned* __restrict__ counts,
    unsigned* __restrict__ offsets, unsigned* __restrict__ alloc,
    unsigned* __restrict__ order)
{
    __shared__ unsigned psum[256];
    __shared__ unsigned bh[256];
    __shared__ unsigned bb[256];
    int tid = threadIdx.x;
    unsigned base = tid * 16;
    unsigned ssum = 0;
    for (int i = 0; i < 16; ++i) ssum += counts[base + i];
    psum[tid] = ssum;
    bh[tid] = 0;
    __syncthreads();
    if (tid == 0) {
        unsigned r = 0;
        for (int i = 0; i < 256; ++i) { unsigned v = psum[i]; psum[i] = r; r += v; }
    }
    __syncthreads();
    unsigned run = psum[tid];
    for (int i = 0; i < 16; ++i) {
        unsigned v = counts[base + i];
        offsets[base + i] = run;
        alloc[base + i]   = run;
        run += v;
        atomicAdd(&bh[min(v >> 4, 255u)], 1u);
    }
    __syncthreads();
    if (tid == 0) {
        unsigned r = 0;
        for (int b = 255; b >= 0; --b) { unsigned v = bh[b]; bb[b] = r; r += v; }
    }
    __syncthreads();
    for (int i = 0; i < 16; ++i) {
        unsigned v = counts[base + i];
        unsigned slot = atomicAdd(&bb[min(v >> 4, 255u)], 1u);
        order[slot] = base + i;
    }
}

// ============================================================================
// K3: scatter point indices into per-tile segments (unchanged).
// ============================================================================
__global__ __launch_bounds__(256) void k3_scatter(
    const float4* __restrict__ pf, unsigned* __restrict__ alloc,
    unsigned* __restrict__ entries)
{
    __shared__ unsigned lcnt[NTILES];
    __shared__ unsigned lbase[NTILES];
    for (int i = threadIdx.x; i < NTILES; i += 256) lcnt[i] = 0;
    __syncthreads();

    int pid = blockIdx.x * 256 + threadIdx.x;
    float4 f = pf[pid];
    unsigned key = __float_as_uint(f.w);
    int X = (int)(key & 511u) - 256;
    int Y = (int)((key >> 9) & 511u) - 256;
    int Z = (int)((key >> 18) & 511u) - 256;
    TileSpan ts = tile_span(X, Y, Z);

    unsigned rnk[2][2][2];
    #pragma unroll
    for (int ez = 0; ez < 2; ++ez) {
        bool okz = (ez == 0) || (ts.tzb > ts.tza);
        #pragma unroll
        for (int ey = 0; ey < 2; ++ey) {
            bool oky = (ey == 0) || (ts.tyb > ts.tya);
            #pragma unroll
            for (int ex = 0; ex < 2; ++ex) {
                bool okx = (ex == 0) || (ts.txb > ts.txa);
                if (okz && oky && okx) {
                    int tt = ((ts.tza + ez) * TPA + (ts.tya + ey)) * TPA + (ts.txa + ex);
                    rnk[ez][ey][ex] = atomicAdd(&lcnt[tt], 1u);
                }
            }
        }
    }
    __syncthreads();
    for (int i = threadIdx.x; i < NTILES; i += 256)
        if (lcnt[i]) lbase[i] = atomicAdd(&alloc[i], lcnt[i]);
    __syncthreads();
    #pragma unroll
    for (int ez = 0; ez < 2; ++ez) {
        bool okz = (ez == 0) || (ts.tzb > ts.tza);
        #pragma unroll
        for (int ey = 0; ey < 2; ++ey) {
            bool oky = (ey == 0) || (ts.tyb > ts.tya);
            #pragma unroll
            for (int ex = 0; ex < 2; ++ex) {
                bool okx = (ex == 0) || (ts.txb > ts.txa);
                if (okz && oky && okx) {
                    int tt = ((ts.tza + ez) * TPA + (ts.tya + ey)) * TPA + (ts.txa + ex);
                    entries[lbase[tt] + rnk[ez][ey][ex]] = (unsigned)pid;
                }
            }
        }
    }
}

// ============================================================================
// K4 v2: fused gather+MLP+splat with
//  (a) per-wave bucket lists (no 4x full-chunk scan),
//  (b) dual gather chains fA/fB (2x outstanding loads, latency overlap),
//  (c) hoisted sO loads shared by the two layer-halves.
// ============================================================================
__global__ __launch_bounds__(256) void k4_fused(
    const float4* __restrict__ pf, const unsigned* __restrict__ entries,
    const unsigned* __restrict__ offsets, const unsigned* __restrict__ alloc,
    const unsigned* __restrict__ order,
    const float* __restrict__ enc, const int* __restrict__ gidx,
    const float* __restrict__ grid, const float* __restrict__ W0,
    const float* __restrict__ b0,   const float* __restrict__ W1,
    const float* __restrict__ b1,   float* __restrict__ out)
{
    __shared__ __attribute__((aligned(16))) float4 sA[CHUNK];   // fx,fy,fz, cx0|cx1|cy0|cy1
    __shared__ __attribute__((aligned(16))) int    sZ[CHUNK];   // st0|st1<<8 (255=out)
    __shared__ __attribute__((aligned(16))) float4 sO[4*CHUNK]; // o[16] planar [q][entry]
    __shared__ unsigned short wlist[4][CHUNK];                  // per-wave hit lists
    __shared__ unsigned wcnt[4];

    int t  = order[blockIdx.x];      // heavy tiles scheduled first
    int tx = t & (TPA-1), ty = (t >> 4) & (TPA-1), tz = t >> 8;
    int ox = tx * TW, oy = ty * TW, oz = tz * TW;

    int tid  = threadIdx.x;
    int lane = tid & 63;
    int w    = tid >> 6;             // wave id, owns z-layers {2w, 2w+1}
    int vxa  = ox + (lane & 7);
    int vya  = oy + (lane >> 3);
    int l0   = 2*w, l1 = 2*w + 1;

    float accA[C_OUT], accB[C_OUT];
    #pragma unroll
    for (int c = 0; c < C_OUT; ++c) { accA[c] = 0.0f; accB[c] = 0.0f; }

    unsigned e0 = offsets[t], e1 = alloc[t];
    for (unsigned base = e0; base < e1; base += CHUNK) {
        int n = min((unsigned)CHUNK, e1 - base);
        if (tid < 4) wcnt[tid] = 0;
        __syncthreads();

        if (tid < n) {
            unsigned p = entries[base + tid];
            float4 f = pf[p];
            unsigned key = __float_as_uint(f.w);
            int X = (int)(key & 511u) - 256;
            int Y = (int)((key >> 9) & 511u) - 256;
            int Z = (int)((key >> 18) & 511u) - 256;
            int cx0 = clampi(X, GW-1),  cx1 = clampi(X+1, GW-1);
            int cy0 = clampi(Y, GH-1),  cy1 = clampi(Y+1, GH-1);
            int cz0 = clampi(Z, GD-1),  cz1 = clampi(Z+1, GD-1);
            unsigned pk = (unsigned)cx0 | ((unsigned)cx1 << 8)
                        | ((unsigned)cy0 << 16) | ((unsigned)cy1 << 24);
            int st0 = ((unsigned)(cz0 - oz) < 8u) ? (cz0 - oz) : 255;
            int st1 = ((unsigned)(cz1 - oz) < 8u) ? (cz1 - oz) : 255;
            sA[tid] = make_float4(f.x, f.y, f.z, __uint_as_float(pk));
            sZ[tid] = st0 | (st1 << 8);
            int w0 = st0 >> 1, w1 = st1 >> 1;   // 0..3 in-tile, 127 out
            if (w0 < 4) wlist[w0][atomicAdd(&wcnt[w0], 1u)] = (unsigned short)tid;
            if ((w1 < 4) & (w1 != w0)) wlist[w1][atomicAdd(&wcnt[w1], 1u)] = (unsigned short)tid;

            // ---- gather: two independent chains (even/odd x corners) ----
            int ray = (int)(p / (unsigned)NSAMP);
            int b   = gidx[ray];
            float fA[C_IN], fB[C_IN];
            {
                const float4* e4 = (const float4*)(enc + (size_t)ray * C_IN);
                #pragma unroll
                for (int q = 0; q < C_IN/4; ++q) {
                    float4 v = e4[q];
                    fA[4*q+0] = v.x; fA[4*q+1] = v.y; fA[4*q+2] = v.z; fA[4*q+3] = v.w;
                    fB[4*q+0] = 0.0f; fB[4*q+1] = 0.0f; fB[4*q+2] = 0.0f; fB[4*q+3] = 0.0f;
                }
            }
            int gza[2] = { cz0, cz1 };
            int gya[2] = { cy0, cy1 };
            float wza[2] = { 1.0f - f.z, f.z };
            float wya[2] = { 1.0f - f.y, f.y };
            float wxa[2] = { 1.0f - f.x, f.x };
            #pragma unroll
            for (int dz = 0; dz < 2; ++dz)
            #pragma unroll
            for (int dy = 0; dy < 2; ++dy) {
                float wzy = wza[dz] * wya[dy];
                size_t rowbase = ((((size_t)b * GD + gza[dz]) * GH + gya[dy]) * GW);
                const float4* gA = (const float4*)(grid + (rowbase + cx0) * C_IN);
                const float4* gB = (const float4*)(grid + (rowbase + cx1) * C_IN);
                float wqA = wzy * wxa[0], wqB = wzy * wxa[1];
                #pragma unroll
                for (int q = 0; q < C_IN/4; ++q) {
                    float4 vA = gA[q];
                    float4 vB = gB[q];
                    fA[4*q+0] = fmaf(wqA, vA.x, fA[4*q+0]);
                    fA[4*q+1] = fmaf(wqA, vA.y, fA[4*q+1]);
                    fA[4*q+2] = fmaf(wqA, vA.z, fA[4*q+2]);
                    fA[4*q+3] = fmaf(wqA, vA.w, fA[4*q+3]);
                    fB[4*q+0] = fmaf(wqB, vB.x, fB[4*q+0]);
                    fB[4*q+1] = fmaf(wqB, vB.y, fB[4*q+1]);
                    fB[4*q+2] = fmaf(wqB, vB.z, fB[4*q+2]);
                    fB[4*q+3] = fmaf(wqB, vB.w, fB[4*q+3]);
                }
            }
            // fold chains: fA := fA + fB (frees fB before MLP)
            #pragma unroll
            for (int i = 0; i < C_IN; ++i) fA[i] += fB[i];

            // ---- MLP (weights wave-uniform -> scalar loads) ----
            float h[C_HID];
            #pragma unroll
            for (int j = 0; j < C_HID; ++j) h[j] = b0[j];
            #pragma unroll
            for (int i = 0; i < C_IN; ++i) {
                float xi = fA[i];
                #pragma unroll
                for (int j = 0; j < C_HID; ++j) h[j] = fmaf(xi, W0[i*C_HID + j], h[j]);
            }
            #pragma unroll
            for (int j = 0; j < C_HID; ++j) h[j] = fmaxf(h[j], 0.0f);

            float o[C_OUT];
            #pragma unroll
            for (int j = 0; j < C_OUT; ++j) o[j] = b1[j];
            #pragma unroll
            for (int i = 0; i < C_HID; ++i) {
                float hi = h[i];
                #pragma unroll
                for (int j = 0; j < C_OUT; ++j) o[j] = fmaf(hi, W1[i*C_OUT + j], o[j]);
            }
            #pragma unroll
            for (int q = 0; q < 4; ++q)
                sO[q*CHUNK + tid] = make_float4(o[4*q+0], o[4*q+1], o[4*q+2], o[4*q+3]);
        }
        __syncthreads();

        // ---- splat: wave walks only ITS hit list ----
        unsigned cnt = wcnt[w];
        for (unsigned i = 0; i < cnt; ++i) {
            int j = wlist[w][i];                 // wave-uniform broadcast
            float4 a = sA[j];
            int zz = sZ[j];
            int st0 = zz & 255, st1 = (zz >> 8) & 255;
            unsigned pk = __float_as_uint(a.w);
            int cx0 = (int)(pk & 255u),         cx1 = (int)((pk >> 8) & 255u);
            int cy0 = (int)((pk >> 16) & 255u), cy1 = (int)(pk >> 24);

            float wx = ((vxa == cx0) ? 1.0f - a.x : 0.0f)
                     + ((vxa == cx1) ? a.x        : 0.0f);
            float wy = ((vya == cy0) ? 1.0f - a.y : 0.0f)
                     + ((vya == cy1) ? a.y        : 0.0f);
            float wxy = wx * wy;

            float4 ov0 = sO[j];
            float4 ov1 = sO[CHUNK + j];
            float4 ov2 = sO[2*CHUNK + j];
            float4 ov3 = sO[3*CHUNK + j];

            bool hitA = (st0 == l0) | (st1 == l0);   // wave-uniform
            if (hitA) {
                float wzA = ((st0 == l0) ? 1.0f - a.z : 0.0f)
                          + ((st1 == l0) ? a.z        : 0.0f);
                float wA = wxy * wzA;
                accA[0]  = fmaf(wA, ov0.x, accA[0]);  accA[1]  = fmaf(wA, ov0.y, accA[1]);
                accA[2]  = fmaf(wA, ov0.z, accA[2]);  accA[3]  = fmaf(wA, ov0.w, accA[3]);
                accA[4]  = fmaf(wA, ov1.x, accA[4]);  accA[5]  = fmaf(wA, ov1.y, accA[5]);
                accA[6]  = fmaf(wA, ov1.z, accA[6]);  accA[7]  = fmaf(wA, ov1.w, accA[7]);
                accA[8]  = fmaf(wA, ov2.x, accA[8]);  accA[9]  = fmaf(wA, ov2.y, accA[9]);
                accA[10] = fmaf(wA, ov2.z, accA[10]); accA[11] = fmaf(wA, ov2.w, accA[11]);
                accA[12] = fmaf(wA, ov3.x, accA[12]); accA[13] = fmaf(wA, ov3.y, accA[13]);
                accA[14] = fmaf(wA, ov3.z, accA[14]); accA[15] = fmaf(wA, ov3.w, accA[15]);
            }
            bool hitB = (st0 == l1) | (st1 == l1);   // wave-uniform
            if (hitB) {
                float wzB = ((st0 == l1) ? 1.0f - a.z : 0.0f)
                          + ((st1 == l1) ? a.z        : 0.0f);
                float wB = wxy * wzB;
                accB[0]  = fmaf(wB, ov0.x, accB[0]);  accB[1]  = fmaf(wB, ov0.y, accB[1]);
                accB[2]  = fmaf(wB, ov0.z, accB[2]);  accB[3]  = fmaf(wB, ov0.w, accB[3]);
                accB[4]  = fmaf(wB, ov1.x, accB[4]);  accB[5]  = fmaf(wB, ov1.y, accB[5]);
                accB[6]  = fmaf(wB, ov1.z, accB[6]);  accB[7]  = fmaf(wB, ov1.w, accB[7]);
                accB[8]  = fmaf(wB, ov2.x, accB[8]);  accB[9]  = fmaf(wB, ov2.y, accB[9]);
                accB[10] = fmaf(wB, ov2.z, accB[10]); accB[11] = fmaf(wB, ov2.w, accB[11]);
                accB[12] = fmaf(wB, ov3.x, accB[12]); accB[13] = fmaf(wB, ov3.y, accB[13]);
                accB[14] = fmaf(wB, ov3.z, accB[14]); accB[15] = fmaf(wB, ov3.w, accB[15]);
            }
        }
        __syncthreads();
    }

    // ---- dense register writeback (full coverage -> no memset needed) ----
    size_t baseA = ((((size_t)(oz + l0)) * GH + vya) * GW + vxa) * C_OUT;
    size_t baseB = ((((size_t)(oz + l1)) * GH + vya) * GW + vxa) * C_OUT;
    #pragma unroll
    for (int q = 0; q < 4; ++q) {
        *(float4*)(out + baseA + 4*q) = make_float4(accA[4*q+0], accA[4*q+1], accA[4*q+2], accA[4*q+3]);
        *(float4*)(out + baseB + 4*q) = make_float4(accB[4*q+0], accB[4*q+1], accB[4*q+2], accB[4*q+3]);
    }
}

// ============================================================================
// Fallback (round-3 fused kernel) if workspace is too small.
// ============================================================================
#define SEGS   8
#define SEGLEN (NSAMP / SEGS)
#define NTHREADS (N_RAYS * SEGS)

__global__ __launch_bounds__(256, 2) void splat_seg_kernel(
    const float* __restrict__ origins, const float* __restrict__ dirs,
    const float* __restrict__ nearv,   const float* __restrict__ farv,
    const float* __restrict__ enc,     const int*   __restrict__ gidx,
    const float* __restrict__ grid,    const float* __restrict__ W0,
    const float* __restrict__ b0,      const float* __restrict__ W1,
    const float* __restrict__ b1,      float* __restrict__ out)
{
    int tid = blockIdx.x * blockDim.x + threadIdx.x;
    if (tid >= NTHREADS) return;
    int ray = tid / SEGS;
    int seg = tid - ray * SEGS;
    float nr = nearv[ray], fr = farv[ray];
    float ox = origins[3*ray+0], oy = origins[3*ray+1], oz = origins[3*ray+2];
    float rdx = dirs[3*ray+0],   rdy = dirs[3*ray+1],   rdz = dirs[3*ray+2];
    int   b  = gidx[ray];
    float accv[8][C_OUT];
    #pragma unroll
    for (int sl = 0; sl < 8; ++sl)
        #pragma unroll
        for (int c = 0; c < C_OUT; ++c) accv[sl][c] = 0.0f;
    int Xp = 0, Yp = 0, Zp = 0;
    #pragma unroll 1
    for (int k = 0; k < SEGLEN; ++k) {
        int s = seg * SEGLEN + k;
        float t  = nr + (fr - nr) * ((float)s * (1.0f / (NSAMP - 1)));
        float px = fmaf(t, rdx, ox);
        float py = fmaf(t, rdy, oy);
        float pz = fmaf(t, rdz, oz);
        float cx = ((px + 1.0f) * (float)GW - 1.0f) * 0.5f;
        float cy = ((py + 1.0f) * (float)GH - 1.0f) * 0.5f;
        float cz = ((pz + 1.0f) * (float)GD - 1.0f) * 0.5f;
        float fxf = floorf(cx), fyf = floorf(cy), fzf = floorf(cz);
        float fx = cx - fxf, fy = cy - fyf, fz = cz - fzf;
        int X = (int)fxf, Y = (int)fyf, Z = (int)fzf;
        if (k == 0) { Xp = X; Yp = Y; Zp = Z; }
        else if (X != Xp || Y != Yp || Z != Zp) {
            bool fXm[2], fYm[2], fZm[2];
            int  vx[2], vy[2], vz[2];
            #pragma unroll
            for (int p = 0; p < 2; ++p) {
                int xo = Xp + ((Xp ^ p) & 1), xn = X + ((X ^ p) & 1);
                fXm[p] = (xo != xn);  vx[p] = clampi(xo, GW-1);
                int yo = Yp + ((Yp ^ p) & 1), yn = Y + ((Y ^ p) & 1);
                fYm[p] = (yo != yn);  vy[p] = clampi(yo, GH-1);
                int zo = Zp + ((Zp ^ p) & 1), zn = Z + ((Z ^ p) & 1);
                fZm[p] = (zo != zn);  vz[p] = clampi(zo, GD-1);
            }
            #pragma unroll
            for (int pxi = 0; pxi < 2; ++pxi)
            #pragma unroll
            for (int pyi = 0; pyi < 2; ++pyi)
            #pragma unroll
            for (int pzi = 0; pzi < 2; ++pzi) {
                const int sl = pxi*4 + pyi*2 + pzi;
                if (fXm[pxi] | fYm[pyi] | fZm[pzi]) {
                    size_t flat = ((((size_t)b * GD + vz[pzi]) * GH + vy[pyi]) * GW + vx[pxi]) * C_OUT;
                    float* op = out + flat;
                    #pragma unroll
                    for (int c = 0; c < C_OUT; ++c) { atomicAdd(op + c, accv[sl][c]); accv[sl][c] = 0.0f; }
                }
            }
            Xp = X; Yp = Y; Zp = Z;
        }
        float feat[C_IN];
        {
            const float4* e4 = (const float4*)(enc + (size_t)ray * C_IN);
            #pragma unroll
            for (int q = 0; q < C_IN/4; ++q) {
                float4 v = e4[q];
                feat[4*q+0] = v.x; feat[4*q+1] = v.y; feat[4*q+2] = v.z; feat[4*q+3] = v.w;
            }
        }
        int gx[2] = { clampi(X, GW-1), clampi(X+1, GW-1) };
        int gy[2] = { clampi(Y, GH-1), clampi(Y+1, GH-1) };
        int gz[2] = { clampi(Z, GD-1), clampi(Z+1, GD-1) };
        float wxa[2] = { 1.0f - fx, fx };
        float wya[2] = { 1.0f - fy, fy };
        float wza[2] = { 1.0f - fz, fz };
        #pragma unroll
        for (int dz = 0; dz < 2; ++dz)
        #pragma unroll
        for (int dy = 0; dy < 2; ++dy)
        #pragma unroll
        for (int dx = 0; dx < 2; ++dx) {
            float w = wza[dz] * wya[dy] * wxa[dx];
            size_t flat = ((((size_t)b * GD + gz[dz]) * GH + gy[dy]) * GW + gx[dx]) * C_IN;
            const float4* g4 = (const float4*)(grid + flat);
            #pragma unroll
            for (int q = 0; q < C_IN/4; ++q) {
                float4 v = g4[q];
                feat[4*q+0] = fmaf(w, v.x, feat[4*q+0]);
                feat[4*q+1] = fmaf(w, v.y, feat[4*q+1]);
                feat[4*q+2] = fmaf(w, v.z, feat[4*q+2]);
                feat[4*q+3] = fmaf(w, v.w, feat[4*q+3]);
            }
        }
        float h[C_HID];
        #pragma unroll
        for (int j = 0; j < C_HID; ++j) h[j] = b0[j];
        #pragma unroll
        for (int i = 0; i < C_IN; ++i) {
            float xi = feat[i];
            #pragma unroll
            for (int j = 0; j < C_HID; ++j) h[j] = fmaf(xi, W0[i*C_HID + j], h[j]);
        }
        #pragma unroll
        for (int j = 0; j < C_HID; ++j) h[j] = fmaxf(h[j], 0.0f);
        float o[C_OUT];
        #pragma unroll
        for (int j = 0; j < C_OUT; ++j) o[j] = b1[j];
        #pragma unroll
        for (int i = 0; i < C_HID; ++i) {
            float hi = h[i];
            #pragma unroll
            for (int j = 0; j < C_OUT; ++j) o[j] = fmaf(hi, W1[i*C_OUT + j], o[j]);
        }
        float wxs[2], wys[2], wzs[2];
        #pragma unroll
        for (int p = 0; p < 2; ++p) {
            wxs[p] = ((X & 1) == p) ? (1.0f - fx) : fx;
            wys[p] = ((Y & 1) == p) ? (1.0f - fy) : fy;
            wzs[p] = ((Z & 1) == p) ? (1.0f - fz) : fz;
        }
        #pragma unroll
        for (int pxi = 0; pxi < 2; ++pxi)
        #pragma unroll
        for (int pyi = 0; pyi < 2; ++pyi)
        #pragma unroll
        for (int pzi = 0; pzi < 2; ++pzi) {
            const int sl = pxi*4 + pyi*2 + pzi;
            float w = wxs[pxi] * wys[pyi] * wzs[pzi];
            #pragma unroll
            for (int c = 0; c < C_OUT; ++c) accv[sl][c] = fmaf(w, o[c], accv[sl][c]);
        }
    }
    #pragma unroll
    for (int pxi = 0; pxi < 2; ++pxi)
    #pragma unroll
    for (int pyi = 0; pyi < 2; ++pyi)
    #pragma unroll
    for (int pzi = 0; pzi < 2; ++pzi) {
        const int sl = pxi*4 + pyi*2 + pzi;
        int vx = clampi(Xp + ((Xp ^ pxi) & 1), GW-1);
        int vy = clampi(Yp + ((Yp ^ pyi) & 1), GH-1);
        int vz = clampi(Zp + ((Zp ^ pzi) & 1), GD-1);
        size_t flat = ((((size_t)b * GD + vz) * GH + vy) * GW + vx) * C_OUT;
        float* op = out + flat;
        #pragma unroll
        for (int c = 0; c < C_OUT; ++c) atomicAdd(op + c, accv[sl][c]);
    }
}

// ============================================================================
extern "C" void kernel_launch(void* const* d_in, const int* in_sizes, int n_in,
                              void* d_out, int out_size, void* d_ws, size_t ws_size,
                              hipStream_t stream) {
    const float* origins = (const float*)d_in[0];
    const float* dirs    = (const float*)d_in[1];
    const float* nearv   = (const float*)d_in[2];
    const float* farv    = (const float*)d_in[3];
    const float* enc     = (const float*)d_in[4];
    const int*   gidx    = (const int*)  d_in[5];
    const float* grid    = (const float*)d_in[6];
    const float* W0      = (const float*)d_in[7];
    const float* b0      = (const float*)d_in[8];
    const float* W1      = (const float*)d_in[9];
    const float* b1      = (const float*)d_in[10];
    float* out = (float*)d_out;

    const size_t PF_B = (size_t)M_PTS * 16;         // 25,165,824
    const size_t EN_B = (size_t)M_PTS * 8 * 4;      // 50,331,648 (hard bound)
    const size_t CT_B = (size_t)NTILES * 4;
    const size_t NEED = PF_B + EN_B + 4 * CT_B;

    if (ws_size < NEED) {
        // fallback: fused register-merged scatter (round-3 path)
        hipMemsetAsync(out, 0, (size_t)out_size * sizeof(float), stream);
        splat_seg_kernel<<<NTHREADS/256, 256, 0, stream>>>(
            origins, dirs, nearv, farv, enc, gidx, grid, W0, b0, W1, b1, out);
        return;
    }

    char* w = (char*)d_ws;
    float4*   pf      = (float4*)   w;              w += PF_B;
    unsigned* entries = (unsigned*) w;              w += EN_B;
    unsigned* counts  = (unsigned*) w;              w += CT_B;
    unsigned* offsets = (unsigned*) w;              w += CT_B;
    unsigned* alloc   = (unsigned*) w;              w += CT_B;
    unsigned* order   = (unsigned*) w;              w += CT_B;

    hipMemsetAsync(counts, 0, CT_B, stream);
    k1_pos<<<M_PTS/256, 256, 0, stream>>>(origins, dirs, nearv, farv, pf, counts);
    k2_scan<<<1, 256, 0, stream>>>(counts, offsets, alloc, order);
    k3_scatter<<<M_PTS/256, 256, 0, stream>>>(pf, alloc, entries);
    k4_fused<<<NTILES, 256, 0, stream>>>(pf, entries, offsets, alloc, order,
                                         enc, gidx, grid, W0, b0, W1, b1, out);
    // K4 writes every output voxel densely -> no output memset needed.
}

// Round 13
// 668.449 us; speedup vs baseline: 1.0581x; 1.0581x over previous
//
#include <hip/hip_runtime.h>

#define N_RAYS 16384
#define NSAMP  96
#define GD 128
#define GH 128
#define GW 128
#define C_IN  32
#define C_HID 32
#define C_OUT 16
#define M_PTS (N_RAYS * NSAMP)       // 1,572,864 (divisible by 256)
#define TPA 16                        // tiles per axis (128/8)
#define NTILES (TPA*TPA*TPA)          // 4096
#define TW 8                          // tile width (voxels)
#define TVOX (TW*TW*TW)               // 512 voxels per tile
#define CHUNK 128                     // entries staged per K4 inner pass

__device__ __forceinline__ int clampi(int v, int hi) { return min(max(v, 0), hi); }

struct TileSpan { int txa, txb, tya, tyb, tza, tzb; };
__device__ __forceinline__ TileSpan tile_span(int X, int Y, int Z) {
    TileSpan s;
    s.txa = clampi(X,   GW-1) >> 3;  s.txb = clampi(X+1, GW-1) >> 3;
    s.tya = clampi(Y,   GH-1) >> 3;  s.tyb = clampi(Y+1, GH-1) >> 3;
    s.tza = clampi(Z,   GD-1) >> 3;  s.tzb = clampi(Z+1, GD-1) >> 3;
    return s;
}

// ============================================================================
// K1 v2: gather+MLP with DEEP LOAD ILP. __launch_bounds__(256,4) lifts the
// VGPR cap to ~128 (4 waves/SIMD = the occupancy r10 measured anyway), and
// the gather issues corner-PAIRS of loads into explicit temps (16 independent
// float4 loads in flight before any FMA consumes them) instead of the
// load-8/consume-8 per-corner chain that serialized ~8 memory round trips.
// ============================================================================
__global__ __launch_bounds__(256, 4) void k1_point(
    const float* __restrict__ origins, const float* __restrict__ dirs,
    const float* __restrict__ nearv,   const float* __restrict__ farv,
    const float* __restrict__ enc,     const int*   __restrict__ gidx,
    const float* __restrict__ grid,    const float* __restrict__ W0,
    const float* __restrict__ b0,      const float* __restrict__ W1,
    const float* __restrict__ b1,
    float4* __restrict__ pf, float4* __restrict__ po, unsigned* __restrict__ counts)
{
    __shared__ unsigned lcnt[NTILES];
    for (int i = threadIdx.x; i < NTILES; i += 256) lcnt[i] = 0;
    __syncthreads();

    int pid = blockIdx.x * 256 + threadIdx.x;     // always < M_PTS (exact grid)
    int ray = pid / NSAMP;
    int s   = pid - ray * NSAMP;

    float nr = nearv[ray], fr = farv[ray];
    float t  = nr + (fr - nr) * ((float)s * (1.0f / (NSAMP - 1)));
    float px = fmaf(t, dirs[ray*3+0], origins[ray*3+0]);
    float py = fmaf(t, dirs[ray*3+1], origins[ray*3+1]);
    float pz = fmaf(t, dirs[ray*3+2], origins[ray*3+2]);
    int   b  = gidx[ray];

    float cx = ((px + 1.0f) * (float)GW - 1.0f) * 0.5f;
    float cy = ((py + 1.0f) * (float)GH - 1.0f) * 0.5f;
    float cz = ((pz + 1.0f) * (float)GD - 1.0f) * 0.5f;
    float fxf = floorf(cx), fyf = floorf(cy), fzf = floorf(cz);
    float fx = cx - fxf, fy = cy - fyf, fz = cz - fzf;
    int X = (int)fxf, Y = (int)fyf, Z = (int)fzf;

    int gx[2] = { clampi(X, GW-1), clampi(X+1, GW-1) };
    int gy[2] = { clampi(Y, GH-1), clampi(Y+1, GH-1) };
    int gz[2] = { clampi(Z, GD-1), clampi(Z+1, GD-1) };
    float wxa[2] = { 1.0f - fx, fx };
    float wya[2] = { 1.0f - fy, fy };
    float wza[2] = { 1.0f - fz, fz };

    // ---- feat starts at the ray encoding ----
    float feat[C_IN];
    {
        const float4* e4 = (const float4*)(enc + (size_t)ray * C_IN);
        #pragma unroll
        for (int q = 0; q < C_IN/4; ++q) {
            float4 v = e4[q];
            feat[4*q+0] = v.x; feat[4*q+1] = v.y; feat[4*q+2] = v.z; feat[4*q+3] = v.w;
        }
    }

    // ---- corner bases & weights (all compile-time indexed) ----
    const float4* cb[8];
    float wc[8];
    #pragma unroll
    for (int dz = 0; dz < 2; ++dz)
    #pragma unroll
    for (int dy = 0; dy < 2; ++dy)
    #pragma unroll
    for (int dx = 0; dx < 2; ++dx) {
        const int ci = dz*4 + dy*2 + dx;
        size_t flat = ((((size_t)b * GD + gz[dz]) * GH + gy[dy]) * GW + gx[dx]) * C_IN;
        cb[ci] = (const float4*)(grid + flat);
        wc[ci] = wza[dz] * wya[dy] * wxa[dx];
    }

    // ---- paired-corner gather: 16 loads in flight, then 64 FMAs ----
    #pragma unroll
    for (int cp = 0; cp < 4; ++cp) {
        const float4* gA = cb[2*cp];
        const float4* gB = cb[2*cp+1];
        float wA = wc[2*cp], wB = wc[2*cp+1];
        float4 tA[8], tB[8];
        #pragma unroll
        for (int q = 0; q < 8; ++q) { tA[q] = gA[q]; tB[q] = gB[q]; }
        #pragma unroll
        for (int q = 0; q < 8; ++q) {
            feat[4*q+0] = fmaf(wA, tA[q].x, fmaf(wB, tB[q].x, feat[4*q+0]));
            feat[4*q+1] = fmaf(wA, tA[q].y, fmaf(wB, tB[q].y, feat[4*q+1]));
            feat[4*q+2] = fmaf(wA, tA[q].z, fmaf(wB, tB[q].z, feat[4*q+2]));
            feat[4*q+3] = fmaf(wA, tA[q].w, fmaf(wB, tB[q].w, feat[4*q+3]));
        }
    }

    // ---- MLP (weights wave-uniform -> scalar loads) ----
    float h[C_HID];
    #pragma unroll
    for (int j = 0; j < C_HID; ++j) h[j] = b0[j];
    #pragma unroll
    for (int i = 0; i < C_IN; ++i) {
        float xi = feat[i];
        #pragma unroll
        for (int j = 0; j < C_HID; ++j) h[j] = fmaf(xi, W0[i*C_HID + j], h[j]);
    }
    #pragma unroll
    for (int j = 0; j < C_HID; ++j) h[j] = fmaxf(h[j], 0.0f);

    float o[C_OUT];
    #pragma unroll
    for (int j = 0; j < C_OUT; ++j) o[j] = b1[j];
    #pragma unroll
    for (int i = 0; i < C_HID; ++i) {
        float hi = h[i];
        #pragma unroll
        for (int j = 0; j < C_OUT; ++j) o[j] = fmaf(hi, W1[i*C_OUT + j], o[j]);
    }

    // ---- store point record (planar, coalesced) ----
    unsigned key = ((unsigned)(X + 256) & 511u)
                 | (((unsigned)(Y + 256) & 511u) << 9)
                 | (((unsigned)(Z + 256) & 511u) << 18);
    pf[pid] = make_float4(fx, fy, fz, __uint_as_float(key));
    #pragma unroll
    for (int q = 0; q < 4; ++q)
        po[(size_t)q * M_PTS + pid] = make_float4(o[4*q+0], o[4*q+1], o[4*q+2], o[4*q+3]);

    // ---- count touched tiles ----
    TileSpan ts = tile_span(X, Y, Z);
    #pragma unroll
    for (int ez = 0; ez < 2; ++ez) {
        if (ez && ts.tzb == ts.tza) continue;
        #pragma unroll
        for (int ey = 0; ey < 2; ++ey) {
            if (ey && ts.tyb == ts.tya) continue;
            #pragma unroll
            for (int ex = 0; ex < 2; ++ex) {
                if (ex && ts.txb == ts.txa) continue;
                int tt = ((ts.tza + ez) * TPA + (ts.tya + ey)) * TPA + (ts.txa + ex);
                atomicAdd(&lcnt[tt], 1u);
            }
        }
    }
    __syncthreads();
    for (int i = threadIdx.x; i < NTILES; i += 256)
        if (lcnt[i]) atomicAdd(&counts[i], lcnt[i]);
}

// ============================================================================
// K2: exclusive scan of 4096 tile counts + heavy-first tile schedule.
// ============================================================================
__global__ __launch_bounds__(256) void k2_scan(
    const unsigned* __restrict__ counts,
    unsigned* __restrict__ offsets, unsigned* __restrict__ alloc,
    unsigned* __restrict__ order)
{
    __shared__ unsigned psum[256];
    __shared__ unsigned bh[256];
    __shared__ unsigned bb[256];
    int tid = threadIdx.x;
    unsigned base = tid * 16;
    unsigned ssum = 0;
    for (int i = 0; i < 16; ++i) ssum += counts[base + i];
    psum[tid] = ssum;
    bh[tid] = 0;
    __syncthreads();
    if (tid == 0) {
        unsigned r = 0;
        for (int i = 0; i < 256; ++i) { unsigned v = psum[i]; psum[i] = r; r += v; }
    }
    __syncthreads();
    unsigned run = psum[tid];
    for (int i = 0; i < 16; ++i) {
        unsigned v = counts[base + i];
        offsets[base + i] = run;
        alloc[base + i]   = run;
        run += v;
        atomicAdd(&bh[min(v >> 4, 255u)], 1u);
    }
    __syncthreads();
    if (tid == 0) {
        unsigned r = 0;
        for (int b = 255; b >= 0; --b) { unsigned v = bh[b]; bb[b] = r; r += v; }
    }
    __syncthreads();
    for (int i = 0; i < 16; ++i) {
        unsigned v = counts[base + i];
        unsigned slot = atomicAdd(&bb[min(v >> 4, 255u)], 1u);
        order[slot] = base + i;
    }
}

// ============================================================================
// K3: scatter point indices into per-tile segments (unchanged).
// ============================================================================
__global__ __launch_bounds__(256) void k3_scatter(
    const float4* __restrict__ pf, unsigned* __restrict__ alloc,
    unsigned* __restrict__ entries)
{
    __shared__ unsigned lcnt[NTILES];
    __shared__ unsigned lbase[NTILES];
    for (int i = threadIdx.x; i < NTILES; i += 256) lcnt[i] = 0;
    __syncthreads();

    int pid = blockIdx.x * 256 + threadIdx.x;
    float4 f = pf[pid];
    unsigned key = __float_as_uint(f.w);
    int X = (int)(key & 511u) - 256;
    int Y = (int)((key >> 9) & 511u) - 256;
    int Z = (int)((key >> 18) & 511u) - 256;
    TileSpan ts = tile_span(X, Y, Z);

    unsigned rnk[2][2][2];
    #pragma unroll
    for (int ez = 0; ez < 2; ++ez) {
        bool okz = (ez == 0) || (ts.tzb > ts.tza);
        #pragma unroll
        for (int ey = 0; ey < 2; ++ey) {
            bool oky = (ey == 0) || (ts.tyb > ts.tya);
            #pragma unroll
            for (int ex = 0; ex < 2; ++ex) {
                bool okx = (ex == 0) || (ts.txb > ts.txa);
                if (okz && oky && okx) {
                    int tt = ((ts.tza + ez) * TPA + (ts.tya + ey)) * TPA + (ts.txa + ex);
                    rnk[ez][ey][ex] = atomicAdd(&lcnt[tt], 1u);
                }
            }
        }
    }
    __syncthreads();
    for (int i = threadIdx.x; i < NTILES; i += 256)
        if (lcnt[i]) lbase[i] = atomicAdd(&alloc[i], lcnt[i]);
    __syncthreads();
    #pragma unroll
    for (int ez = 0; ez < 2; ++ez) {
        bool okz = (ez == 0) || (ts.tzb > ts.tza);
        #pragma unroll
        for (int ey = 0; ey < 2; ++ey) {
            bool oky = (ey == 0) || (ts.tyb > ts.tya);
            #pragma unroll
            for (int ex = 0; ex < 2; ++ex) {
                bool okx = (ex == 0) || (ts.txb > ts.txa);
                if (okz && oky && okx) {
                    int tt = ((ts.tza + ez) * TPA + (ts.tya + ey)) * TPA + (ts.txa + ex);
                    entries[lbase[tt] + rnk[ez][ey][ex]] = (unsigned)pid;
                }
            }
        }
    }
}

// ============================================================================
// K4: register accumulation + batched wave-uniform z skip + heavy-first
// schedule + wave-uniform per-layer FMA guards (r10 version, unchanged).
// ============================================================================
__global__ __launch_bounds__(256) void k4_accum(
    const float4* __restrict__ pf, const float4* __restrict__ po,
    const unsigned* __restrict__ entries, const unsigned* __restrict__ offsets,
    const unsigned* __restrict__ alloc, const unsigned* __restrict__ order,
    float* __restrict__ out)
{
    __shared__ __attribute__((aligned(16))) float4 sA[CHUNK]; // fx,fy,fz, cx0|cx1|cy0|cy1
    __shared__ __attribute__((aligned(16))) int    sZ[CHUNK]; // st0|st1<<8 (255=out)
    __shared__ __attribute__((aligned(16))) float4 sO[4*CHUNK]; // o[16] planar [q][entry]

    int t  = order[blockIdx.x];      // heavy tiles scheduled first
    int tx = t & (TPA-1), ty = (t >> 4) & (TPA-1), tz = t >> 8;
    int ox = tx * TW, oy = ty * TW, oz = tz * TW;

    int tid  = threadIdx.x;
    int lane = tid & 63;
    int w    = tid >> 6;             // wave id, owns z-layers {2w, 2w+1}
    int vxa  = ox + (lane & 7);
    int vya  = oy + (lane >> 3);
    int l0   = 2*w, l1 = 2*w + 1;

    float accA[C_OUT], accB[C_OUT];
    #pragma unroll
    for (int c = 0; c < C_OUT; ++c) { accA[c] = 0.0f; accB[c] = 0.0f; }

    unsigned e0 = offsets[t], e1 = alloc[t];
    for (unsigned base = e0; base < e1; base += CHUNK) {
        int n = min((unsigned)CHUNK, e1 - base);
        if (tid < CHUNK) {
            if (tid < n) {
                unsigned p = entries[base + tid];
                float4 f = pf[p];
                unsigned key = __float_as_uint(f.w);
                int X = (int)(key & 511u) - 256;
                int Y = (int)((key >> 9) & 511u) - 256;
                int Z = (int)((key >> 18) & 511u) - 256;
                int cx0 = clampi(X, GW-1),  cx1 = clampi(X+1, GW-1);
                int cy0 = clampi(Y, GH-1),  cy1 = clampi(Y+1, GH-1);
                int cz0 = clampi(Z, GD-1),  cz1 = clampi(Z+1, GD-1);
                unsigned pk = (unsigned)cx0 | ((unsigned)cx1 << 8)
                            | ((unsigned)cy0 << 16) | ((unsigned)cy1 << 24);
                int st0 = ((unsigned)(cz0 - oz) < 8u) ? (cz0 - oz) : 255;
                int st1 = ((unsigned)(cz1 - oz) < 8u) ? (cz1 - oz) : 255;
                sA[tid] = make_float4(f.x, f.y, f.z, __uint_as_float(pk));
                sZ[tid] = st0 | (st1 << 8);
                #pragma unroll
                for (int q = 0; q < 4; ++q)
                    sO[q*CHUNK + tid] = po[(size_t)q * M_PTS + p];
            } else {
                sZ[tid] = 255 | (255 << 8);   // sentinel: hits no wave
            }
        }
        __syncthreads();

        const int4* sZ4 = (const int4*)sZ;
        int n4 = (n + 3) & ~3;
        for (int jb = 0; jb < n4; jb += 4) {
            int4 z4 = sZ4[jb >> 2];                     // broadcast batch of 4
            #pragma unroll
            for (int k = 0; k < 4; ++k) {
                int zz  = (k==0) ? z4.x : (k==1) ? z4.y : (k==2) ? z4.z : z4.w;
                int st0 = zz & 255, st1 = (zz >> 8) & 255;
                bool hitA = (st0 == l0) | (st1 == l0);   // wave-uniform
                bool hitB = (st0 == l1) | (st1 == l1);   // wave-uniform
                if (!(hitA | hitB)) continue;            // uniform skip
                int j = jb + k;
                float4 a = sA[j];
                unsigned pk = __float_as_uint(a.w);
                int cx0 = (int)(pk & 255u),         cx1 = (int)((pk >> 8) & 255u);
                int cy0 = (int)((pk >> 16) & 255u), cy1 = (int)(pk >> 24);

                float wx = ((vxa == cx0) ? 1.0f - a.x : 0.0f)
                         + ((vxa == cx1) ? a.x        : 0.0f);
                float wy = ((vya == cy0) ? 1.0f - a.y : 0.0f)
                         + ((vya == cy1) ? a.y        : 0.0f);
                float wxy = wx * wy;

                if (hitA) {
                    float wzA = ((st0 == l0) ? 1.0f - a.z : 0.0f)
                              + ((st1 == l0) ? a.z        : 0.0f);
                    float wA = wxy * wzA;
                    #pragma unroll
                    for (int q = 0; q < 4; ++q) {
                        float4 ov = sO[q*CHUNK + j];
                        accA[4*q+0] = fmaf(wA, ov.x, accA[4*q+0]);
                        accA[4*q+1] = fmaf(wA, ov.y, accA[4*q+1]);
                        accA[4*q+2] = fmaf(wA, ov.z, accA[4*q+2]);
                        accA[4*q+3] = fmaf(wA, ov.w, accA[4*q+3]);
                    }
                }
                if (hitB) {
                    float wzB = ((st0 == l1) ? 1.0f - a.z : 0.0f)
                              + ((st1 == l1) ? a.z        : 0.0f);
                    float wB = wxy * wzB;
                    #pragma unroll
                    for (int q = 0; q < 4; ++q) {
                        float4 ov = sO[q*CHUNK + j];
                        accB[4*q+0] = fmaf(wB, ov.x, accB[4*q+0]);
                        accB[4*q+1] = fmaf(wB, ov.y, accB[4*q+1]);
                        accB[4*q+2] = fmaf(wB, ov.z, accB[4*q+2]);
                        accB[4*q+3] = fmaf(wB, ov.w, accB[4*q+3]);
                    }
                }
            }
        }
        __syncthreads();
    }

    // ---- dense register writeback (full coverage -> no memset needed) ----
    size_t baseA = ((((size_t)(oz + l0)) * GH + vya) * GW + vxa) * C_OUT;
    size_t baseB = ((((size_t)(oz + l1)) * GH + vya) * GW + vxa) * C_OUT;
    #pragma unroll
    for (int q = 0; q < 4; ++q) {
        *(float4*)(out + baseA + 4*q) = make_float4(accA[4*q+0], accA[4*q+1], accA[4*q+2], accA[4*q+3]);
        *(float4*)(out + baseB + 4*q) = make_float4(accB[4*q+0], accB[4*q+1], accB[4*q+2], accB[4*q+3]);
    }
}

// ============================================================================
// Fallback (round-3 fused kernel) if workspace is too small.
// ============================================================================
#define SEGS   8
#define SEGLEN (NSAMP / SEGS)
#define NTHREADS (N_RAYS * SEGS)

__global__ __launch_bounds__(256, 2) void splat_seg_kernel(
    const float* __restrict__ origins, const float* __restrict__ dirs,
    const float* __restrict__ nearv,   const float* __restrict__ farv,
    const float* __restrict__ enc,     const int*   __restrict__ gidx,
    const float* __restrict__ grid,    const float* __restrict__ W0,
    const float* __restrict__ b0,      const float* __restrict__ W1,
    const float* __restrict__ b1,      float* __restrict__ out)
{
    int tid = blockIdx.x * blockDim.x + threadIdx.x;
    if (tid >= NTHREADS) return;
    int ray = tid / SEGS;
    int seg = tid - ray * SEGS;
    float nr = nearv[ray], fr = farv[ray];
    float ox = origins[3*ray+0], oy = origins[3*ray+1], oz = origins[3*ray+2];
    float rdx = dirs[3*ray+0],   rdy = dirs[3*ray+1],   rdz = dirs[3*ray+2];
    int   b  = gidx[ray];
    float accv[8][C_OUT];
    #pragma unroll
    for (int sl = 0; sl < 8; ++sl)
        #pragma unroll
        for (int c = 0; c < C_OUT; ++c) accv[sl][c] = 0.0f;
    int Xp = 0, Yp = 0, Zp = 0;
    #pragma unroll 1
    for (int k = 0; k < SEGLEN; ++k) {
        int s = seg * SEGLEN + k;
        float t  = nr + (fr - nr) * ((float)s * (1.0f / (NSAMP - 1)));
        float px = fmaf(t, rdx, ox);
        float py = fmaf(t, rdy, oy);
        float pz = fmaf(t, rdz, oz);
        float cx = ((px + 1.0f) * (float)GW - 1.0f) * 0.5f;
        float cy = ((py + 1.0f) * (float)GH - 1.0f) * 0.5f;
        float cz = ((pz + 1.0f) * (float)GD - 1.0f) * 0.5f;
        float fxf = floorf(cx), fyf = floorf(cy), fzf = floorf(cz);
        float fx = cx - fxf, fy = cy - fyf, fz = cz - fzf;
        int X = (int)fxf, Y = (int)fyf, Z = (int)fzf;
        if (k == 0) { Xp = X; Yp = Y; Zp = Z; }
        else if (X != Xp || Y != Yp || Z != Zp) {
            bool fXm[2], fYm[2], fZm[2];
            int  vx[2], vy[2], vz[2];
            #pragma unroll
            for (int p = 0; p < 2; ++p) {
                int xo = Xp + ((Xp ^ p) & 1), xn = X + ((X ^ p) & 1);
                fXm[p] = (xo != xn);  vx[p] = clampi(xo, GW-1);
                int yo = Yp + ((Yp ^ p) & 1), yn = Y + ((Y ^ p) & 1);
                fYm[p] = (yo != yn);  vy[p] = clampi(yo, GH-1);
                int zo = Zp + ((Zp ^ p) & 1), zn = Z + ((Z ^ p) & 1);
                fZm[p] = (zo != zn);  vz[p] = clampi(zo, GD-1);
            }
            #pragma unroll
            for (int pxi = 0; pxi < 2; ++pxi)
            #pragma unroll
            for (int pyi = 0; pyi < 2; ++pyi)
            #pragma unroll
            for (int pzi = 0; pzi < 2; ++pzi) {
                const int sl = pxi*4 + pyi*2 + pzi;
                if (fXm[pxi] | fYm[pyi] | fZm[pzi]) {
                    size_t flat = ((((size_t)b * GD + vz[pzi]) * GH + vy[pyi]) * GW + vx[pxi]) * C_OUT;
                    float* op = out + flat;
                    #pragma unroll
                    for (int c = 0; c < C_OUT; ++c) { atomicAdd(op + c, accv[sl][c]); accv[sl][c] = 0.0f; }
                }
            }
            Xp = X; Yp = Y; Zp = Z;
        }
        float feat[C_IN];
        {
            const float4* e4 = (const float4*)(enc + (size_t)ray * C_IN);
            #pragma unroll
            for (int q = 0; q < C_IN/4; ++q) {
                float4 v = e4[q];
                feat[4*q+0] = v.x; feat[4*q+1] = v.y; feat[4*q+2] = v.z; feat[4*q+3] = v.w;
            }
        }
        int gx[2] = { clampi(X, GW-1), clampi(X+1, GW-1) };
        int gy[2] = { clampi(Y, GH-1), clampi(Y+1, GH-1) };
        int gz[2] = { clampi(Z, GD-1), clampi(Z+1, GD-1) };
        float wxa[2] = { 1.0f - fx, fx };
        float wya[2] = { 1.0f - fy, fy };
        float wza[2] = { 1.0f - fz, fz };
        #pragma unroll
        for (int dz = 0; dz < 2; ++dz)
        #pragma unroll
        for (int dy = 0; dy < 2; ++dy)
        #pragma unroll
        for (int dx = 0; dx < 2; ++dx) {
            float w = wza[dz] * wya[dy] * wxa[dx];
            size_t flat = ((((size_t)b * GD + gz[dz]) * GH + gy[dy]) * GW + gx[dx]) * C_IN;
            const float4* g4 = (const float4*)(grid + flat);
            #pragma unroll
            for (int q = 0; q < C_IN/4; ++q) {
                float4 v = g4[q];
                feat[4*q+0] = fmaf(w, v.x, feat[4*q+0]);
                feat[4*q+1] = fmaf(w, v.y, feat[4*q+1]);
                feat[4*q+2] = fmaf(w, v.z, feat[4*q+2]);
                feat[4*q+3] = fmaf(w, v.w, feat[4*q+3]);
            }
        }
        float h[C_HID];
        #pragma unroll
        for (int j = 0; j < C_HID; ++j) h[j] = b0[j];
        #pragma unroll
        for (int i = 0; i < C_IN; ++i) {
            float xi = feat[i];
            #pragma unroll
            for (int j = 0; j < C_HID; ++j) h[j] = fmaf(xi, W0[i*C_HID + j], h[j]);
        }
        #pragma unroll
        for (int j = 0; j < C_HID; ++j) h[j] = fmaxf(h[j], 0.0f);
        float o[C_OUT];
        #pragma unroll
        for (int j = 0; j < C_OUT; ++j) o[j] = b1[j];
        #pragma unroll
        for (int i = 0; i < C_HID; ++i) {
            float hi = h[i];
            #pragma unroll
            for (int j = 0; j < C_OUT; ++j) o[j] = fmaf(hi, W1[i*C_OUT + j], o[j]);
        }
        float wxs[2], wys[2], wzs[2];
        #pragma unroll
        for (int p = 0; p < 2; ++p) {
            wxs[p] = ((X & 1) == p) ? (1.0f - fx) : fx;
            wys[p] = ((Y & 1) == p) ? (1.0f - fy) : fy;
            wzs[p] = ((Z & 1) == p) ? (1.0f - fz) : fz;
        }
        #pragma unroll
        for (int pxi = 0; pxi < 2; ++pxi)
        #pragma unroll
        for (int pyi = 0; pyi < 2; ++pyi)
        #pragma unroll
        for (int pzi = 0; pzi < 2; ++pzi) {
            const int sl = pxi*4 + pyi*2 + pzi;
            float w = wxs[pxi] * wys[pyi] * wzs[pzi];
            #pragma unroll
            for (int c = 0; c < C_OUT; ++c) accv[sl][c] = fmaf(w, o[c], accv[sl][c]);
        }
    }
    #pragma unroll
    for (int pxi = 0; pxi < 2; ++pxi)
    #pragma unroll
    for (int pyi = 0; pyi < 2; ++pyi)
    #pragma unroll
    for (int pzi = 0; pzi < 2; ++pzi) {
        const int sl = pxi*4 + pyi*2 + pzi;
        int vx = clampi(Xp + ((Xp ^ pxi) & 1), GW-1);
        int vy = clampi(Yp + ((Yp ^ pyi) & 1), GH-1);
        int vz = clampi(Zp + ((Zp ^ pzi) & 1), GD-1);
        size_t flat = ((((size_t)b * GD + vz) * GH + vy) * GW + vx) * C_OUT;
        float* op = out + flat;
        #pragma unroll
        for (int c = 0; c < C_OUT; ++c) atomicAdd(op + c, accv[sl][c]);
    }
}

// ============================================================================
extern "C" void kernel_launch(void* const* d_in, const int* in_sizes, int n_in,
                              void* d_out, int out_size, void* d_ws, size_t ws_size,
                              hipStream_t stream) {
    const float* origins = (const float*)d_in[0];
    const float* dirs    = (const float*)d_in[1];
    const float* nearv   = (const float*)d_in[2];
    const float* farv    = (const float*)d_in[3];
    const float* enc     = (const float*)d_in[4];
    const int*   gidx    = (const int*)  d_in[5];
    const float* grid    = (const float*)d_in[6];
    const float* W0      = (const float*)d_in[7];
    const float* b0      = (const float*)d_in[8];
    const float* W1      = (const float*)d_in[9];
    const float* b1      = (const float*)d_in[10];
    float* out = (float*)d_out;

    const size_t PF_B = (size_t)M_PTS * 16;         // 25,165,824
    const size_t PO_B = (size_t)M_PTS * 64;         // 100,663,296
    const size_t EN_B = (size_t)M_PTS * 8 * 4;      // 50,331,648 (hard bound)
    const size_t CT_B = (size_t)NTILES * 4;
    const size_t NEED = PF_B + PO_B + EN_B + 4 * CT_B;

    if (ws_size < NEED) {
        // fallback: fused register-merged scatter (round-3 path)
        hipMemsetAsync(out, 0, (size_t)out_size * sizeof(float), stream);
        splat_seg_kernel<<<NTHREADS/256, 256, 0, stream>>>(
            origins, dirs, nearv, farv, enc, gidx, grid, W0, b0, W1, b1, out);
        return;
    }

    char* w = (char*)d_ws;
    float4*   pf      = (float4*)   w;              w += PF_B;
    float4*   po      = (float4*)   w;              w += PO_B;
    unsigned* entries = (unsigned*) w;              w += EN_B;
    unsigned* counts  = (unsigned*) w;              w += CT_B;
    unsigned* offsets = (unsigned*) w;              w += CT_B;
    unsigned* alloc   = (unsigned*) w;              w += CT_B;
    unsigned* order   = (unsigned*) w;              w += CT_B;

    hipMemsetAsync(counts, 0, CT_B, stream);
    k1_point<<<M_PTS/256, 256, 0, stream>>>(origins, dirs, nearv, farv, enc, gidx,
                                            grid, W0, b0, W1, b1, pf, po, counts);
    k2_scan<<<1, 256, 0, stream>>>(counts, offsets, alloc, order);
    k3_scatter<<<M_PTS/256, 256, 0, stream>>>(pf, alloc, entries);
    k4_accum<<<NTILES, 256, 0, stream>>>(pf, po, entries, offsets, alloc, order, out);
    // K4 writes every output voxel densely -> no output memset needed.
}

// Round 14
// 511.986 us; speedup vs baseline: 1.3815x; 1.3056x over previous
//
#include <hip/hip_runtime.h>

#define N_RAYS 16384
#define NSAMP  96
#define GD 128
#define GH 128
#define GW 128
#define C_IN  32
#define C_HID 32
#define C_OUT 16
#define M_PTS (N_RAYS * NSAMP)       // 1,572,864 (divisible by 256)
#define TPA 16                        // tiles per axis (128/8)
#define NTILES (TPA*TPA*TPA)          // 4096
#define TW 8                          // tile width (voxels)
#define TVOX (TW*TW*TW)               // 512 voxels per tile
#define CHUNK 128                     // entries staged per K4 inner pass

__device__ __forceinline__ int clampi(int v, int hi) { return min(max(v, 0), hi); }

struct TileSpan { int txa, txb, tya, tyb, tza, tzb; };
__device__ __forceinline__ TileSpan tile_span(int X, int Y, int Z) {
    TileSpan s;
    s.txa = clampi(X,   GW-1) >> 3;  s.txb = clampi(X+1, GW-1) >> 3;
    s.tya = clampi(Y,   GH-1) >> 3;  s.tyb = clampi(Y+1, GH-1) >> 3;
    s.tza = clampi(Z,   GD-1) >> 3;  s.tzb = clampi(Z+1, GD-1) >> 3;
    return s;
}

// ============================================================================
// K1 v3: WAVE-COOPERATIVE COALESCED GATHER.
// Phase A: each thread computes its point's 8 (corner offset, weight) -> LDS.
// Phase B: one wave-instruction gathers ONE point: lane l loads corner l>>3,
//   quad l&7 (8 lanes per corner are 128 B contiguous -> ~16 cache-line
//   requests/instr vs ~50-64 for the per-thread scattered float4 gather).
//   Lane (p,q) accumulates feat-quad q of point p across the 8-corner loop
//   (no shuffles), then writes sFeat with +p slot rotation (bank spread).
// Phase C: thread reads its own feat (rotated, compile-time indices), adds
//   enc, runs the unchanged MLP + stores + histogram (lcnt reuses sOffW LDS).
// LDS 48 KB -> 3 blocks/CU -> 6 waves/SIMD.
// ============================================================================
__global__ __launch_bounds__(256) void k1_point(
    const float* __restrict__ origins, const float* __restrict__ dirs,
    const float* __restrict__ nearv,   const float* __restrict__ farv,
    const float* __restrict__ enc,     const int*   __restrict__ gidx,
    const float* __restrict__ grid,    const float* __restrict__ W0,
    const float* __restrict__ b0,      const float* __restrict__ W1,
    const float* __restrict__ b1,
    float4* __restrict__ pf, float4* __restrict__ po, unsigned* __restrict__ counts)
{
    __shared__ __attribute__((aligned(16))) char smem[49152];
    uint2*    sOffW = (uint2*)smem;              // [256][8], 16 KB (dead after B)
    float4*   sFeat = (float4*)(smem + 16384);   // [256][8], 32 KB
    unsigned* lcnt  = (unsigned*)smem;           // 16 KB, reuses sOffW region

    int tid = threadIdx.x;
    int pid = blockIdx.x * 256 + tid;            // always < M_PTS (exact grid)
    int ray = pid / NSAMP;
    int s   = pid - ray * NSAMP;

    // ---- phase A: position, corner offsets + weights -> LDS ----
    float nr = nearv[ray], fr = farv[ray];
    float t  = nr + (fr - nr) * ((float)s * (1.0f / (NSAMP - 1)));
    float px = fmaf(t, dirs[ray*3+0], origins[ray*3+0]);
    float py = fmaf(t, dirs[ray*3+1], origins[ray*3+1]);
    float pz = fmaf(t, dirs[ray*3+2], origins[ray*3+2]);
    int   b  = gidx[ray];

    float cx = ((px + 1.0f) * (float)GW - 1.0f) * 0.5f;
    float cy = ((py + 1.0f) * (float)GH - 1.0f) * 0.5f;
    float cz = ((pz + 1.0f) * (float)GD - 1.0f) * 0.5f;
    float fxf = floorf(cx), fyf = floorf(cy), fzf = floorf(cz);
    float fx = cx - fxf, fy = cy - fyf, fz = cz - fzf;
    int X = (int)fxf, Y = (int)fyf, Z = (int)fzf;

    int gx[2] = { clampi(X, GW-1), clampi(X+1, GW-1) };
    int gy[2] = { clampi(Y, GH-1), clampi(Y+1, GH-1) };
    int gz[2] = { clampi(Z, GD-1), clampi(Z+1, GD-1) };
    float wxa[2] = { 1.0f - fx, fx };
    float wya[2] = { 1.0f - fy, fy };
    float wza[2] = { 1.0f - fz, fz };

    #pragma unroll
    for (int dz = 0; dz < 2; ++dz)
    #pragma unroll
    for (int dy = 0; dy < 2; ++dy)
    #pragma unroll
    for (int dx = 0; dx < 2; ++dx) {
        const int ci = dz*4 + dy*2 + dx;
        unsigned flat = ((((unsigned)b * GD + gz[dz]) * GH + gy[dy]) * GW + gx[dx]) * C_IN;
        float w = wza[dz] * wya[dy] * wxa[dx];
        sOffW[tid*8 + ci] = make_uint2(flat, __float_as_uint(w));
    }
    __syncthreads();

    // ---- phase B: cooperative gather, 1 instr = 1 whole point ----
    int lane  = tid & 63;
    int wbase = tid & ~63;           // first block-local point of this wave
    int sub   = lane >> 3;           // point-in-group 0..7
    int q     = lane & 7;            // quad 0..7
    #pragma unroll
    for (int g = 0; g < 8; ++g) {
        int p = wbase + g*8 + sub;   // block-local point this lane serves
        float4 acc = make_float4(0.0f, 0.0f, 0.0f, 0.0f);
        #pragma unroll
        for (int c = 0; c < 8; ++c) {
            uint2 ow = sOffW[p*8 + c];               // 8-lane broadcast
            const float4* src = (const float4*)(grid + ow.x);
            float4 v = src[q];                       // coalesced: 128 B/corner
            float wgt = __uint_as_float(ow.y);
            acc.x = fmaf(wgt, v.x, acc.x);
            acc.y = fmaf(wgt, v.y, acc.y);
            acc.z = fmaf(wgt, v.z, acc.z);
            acc.w = fmaf(wgt, v.w, acc.w);
        }
        sFeat[p*8 + ((q + p) & 7)] = acc;            // rotated slot (bank spread)
    }
    __syncthreads();

    // ---- phase C: feat = enc + gathered, MLP, stores, histogram ----
    float feat[C_IN];
    {
        const float4* e4 = (const float4*)(enc + (size_t)ray * C_IN);
        #pragma unroll
        for (int qq = 0; qq < 8; ++qq) {
            float4 fv = sFeat[tid*8 + ((qq + tid) & 7)];
            float4 ev = e4[qq];
            feat[4*qq+0] = fv.x + ev.x;
            feat[4*qq+1] = fv.y + ev.y;
            feat[4*qq+2] = fv.z + ev.z;
            feat[4*qq+3] = fv.w + ev.w;
        }
    }
    // init histogram over the dead sOffW region (sFeat reads above are done
    // per-thread; lcnt region != sFeat region, no overlap)
    for (int i = tid; i < NTILES; i += 256) lcnt[i] = 0;

    float h[C_HID];
    #pragma unroll
    for (int j = 0; j < C_HID; ++j) h[j] = b0[j];
    #pragma unroll
    for (int i = 0; i < C_IN; ++i) {
        float xi = feat[i];
        #pragma unroll
        for (int j = 0; j < C_HID; ++j) h[j] = fmaf(xi, W0[i*C_HID + j], h[j]);
    }
    #pragma unroll
    for (int j = 0; j < C_HID; ++j) h[j] = fmaxf(h[j], 0.0f);

    float o[C_OUT];
    #pragma unroll
    for (int j = 0; j < C_OUT; ++j) o[j] = b1[j];
    #pragma unroll
    for (int i = 0; i < C_HID; ++i) {
        float hi = h[i];
        #pragma unroll
        for (int j = 0; j < C_OUT; ++j) o[j] = fmaf(hi, W1[i*C_OUT + j], o[j]);
    }

    unsigned key = ((unsigned)(X + 256) & 511u)
                 | (((unsigned)(Y + 256) & 511u) << 9)
                 | (((unsigned)(Z + 256) & 511u) << 18);
    pf[pid] = make_float4(fx, fy, fz, __uint_as_float(key));
    #pragma unroll
    for (int qq = 0; qq < 4; ++qq)
        po[(size_t)qq * M_PTS + pid] = make_float4(o[4*qq+0], o[4*qq+1], o[4*qq+2], o[4*qq+3]);

    __syncthreads();                 // lcnt fully zeroed before atomics
    TileSpan ts = tile_span(X, Y, Z);
    #pragma unroll
    for (int ez = 0; ez < 2; ++ez) {
        if (ez && ts.tzb == ts.tza) continue;
        #pragma unroll
        for (int ey = 0; ey < 2; ++ey) {
            if (ey && ts.tyb == ts.tya) continue;
            #pragma unroll
            for (int ex = 0; ex < 2; ++ex) {
                if (ex && ts.txb == ts.txa) continue;
                int tt = ((ts.tza + ez) * TPA + (ts.tya + ey)) * TPA + (ts.txa + ex);
                atomicAdd(&lcnt[tt], 1u);
            }
        }
    }
    __syncthreads();
    for (int i = tid; i < NTILES; i += 256)
        if (lcnt[i]) atomicAdd(&counts[i], lcnt[i]);
}

// ============================================================================
// K2: exclusive scan of 4096 tile counts + heavy-first tile schedule.
// ============================================================================
__global__ __launch_bounds__(256) void k2_scan(
    const unsigned* __restrict__ counts,
    unsigned* __restrict__ offsets, unsigned* __restrict__ alloc,
    unsigned* __restrict__ order)
{
    __shared__ unsigned psum[256];
    __shared__ unsigned bh[256];
    __shared__ unsigned bb[256];
    int tid = threadIdx.x;
    unsigned base = tid * 16;
    unsigned ssum = 0;
    for (int i = 0; i < 16; ++i) ssum += counts[base + i];
    psum[tid] = ssum;
    bh[tid] = 0;
    __syncthreads();
    if (tid == 0) {
        unsigned r = 0;
        for (int i = 0; i < 256; ++i) { unsigned v = psum[i]; psum[i] = r; r += v; }
    }
    __syncthreads();
    unsigned run = psum[tid];
    for (int i = 0; i < 16; ++i) {
        unsigned v = counts[base + i];
        offsets[base + i] = run;
        alloc[base + i]   = run;
        run += v;
        atomicAdd(&bh[min(v >> 4, 255u)], 1u);
    }
    __syncthreads();
    if (tid == 0) {
        unsigned r = 0;
        for (int b = 255; b >= 0; --b) { unsigned v = bh[b]; bb[b] = r; r += v; }
    }
    __syncthreads();
    for (int i = 0; i < 16; ++i) {
        unsigned v = counts[base + i];
        unsigned slot = atomicAdd(&bb[min(v >> 4, 255u)], 1u);
        order[slot] = base + i;
    }
}

// ============================================================================
// K3: scatter point indices into per-tile segments (unchanged).
// ============================================================================
__global__ __launch_bounds__(256) void k3_scatter(
    const float4* __restrict__ pf, unsigned* __restrict__ alloc,
    unsigned* __restrict__ entries)
{
    __shared__ unsigned lcnt[NTILES];
    __shared__ unsigned lbase[NTILES];
    for (int i = threadIdx.x; i < NTILES; i += 256) lcnt[i] = 0;
    __syncthreads();

    int pid = blockIdx.x * 256 + threadIdx.x;
    float4 f = pf[pid];
    unsigned key = __float_as_uint(f.w);
    int X = (int)(key & 511u) - 256;
    int Y = (int)((key >> 9) & 511u) - 256;
    int Z = (int)((key >> 18) & 511u) - 256;
    TileSpan ts = tile_span(X, Y, Z);

    unsigned rnk[2][2][2];
    #pragma unroll
    for (int ez = 0; ez < 2; ++ez) {
        bool okz = (ez == 0) || (ts.tzb > ts.tza);
        #pragma unroll
        for (int ey = 0; ey < 2; ++ey) {
            bool oky = (ey == 0) || (ts.tyb > ts.tya);
            #pragma unroll
            for (int ex = 0; ex < 2; ++ex) {
                bool okx = (ex == 0) || (ts.txb > ts.txa);
                if (okz && oky && okx) {
                    int tt = ((ts.tza + ez) * TPA + (ts.tya + ey)) * TPA + (ts.txa + ex);
                    rnk[ez][ey][ex] = atomicAdd(&lcnt[tt], 1u);
                }
            }
        }
    }
    __syncthreads();
    for (int i = threadIdx.x; i < NTILES; i += 256)
        if (lcnt[i]) lbase[i] = atomicAdd(&alloc[i], lcnt[i]);
    __syncthreads();
    #pragma unroll
    for (int ez = 0; ez < 2; ++ez) {
        bool okz = (ez == 0) || (ts.tzb > ts.tza);
        #pragma unroll
        for (int ey = 0; ey < 2; ++ey) {
            bool oky = (ey == 0) || (ts.tyb > ts.tya);
            #pragma unroll
            for (int ex = 0; ex < 2; ++ex) {
                bool okx = (ex == 0) || (ts.txb > ts.txa);
                if (okz && oky && okx) {
                    int tt = ((ts.tza + ez) * TPA + (ts.tya + ey)) * TPA + (ts.txa + ex);
                    entries[lbase[tt] + rnk[ez][ey][ex]] = (unsigned)pid;
                }
            }
        }
    }
}

// ============================================================================
// K4: register accumulation + batched wave-uniform z skip + heavy-first
// schedule + wave-uniform per-layer FMA guards (r10 version, unchanged).
// ============================================================================
__global__ __launch_bounds__(256) void k4_accum(
    const float4* __restrict__ pf, const float4* __restrict__ po,
    const unsigned* __restrict__ entries, const unsigned* __restrict__ offsets,
    const unsigned* __restrict__ alloc, const unsigned* __restrict__ order,
    float* __restrict__ out)
{
    __shared__ __attribute__((aligned(16))) float4 sA[CHUNK]; // fx,fy,fz, cx0|cx1|cy0|cy1
    __shared__ __attribute__((aligned(16))) int    sZ[CHUNK]; // st0|st1<<8 (255=out)
    __shared__ __attribute__((aligned(16))) float4 sO[4*CHUNK]; // o[16] planar [q][entry]

    int t  = order[blockIdx.x];      // heavy tiles scheduled first
    int tx = t & (TPA-1), ty = (t >> 4) & (TPA-1), tz = t >> 8;
    int ox = tx * TW, oy = ty * TW, oz = tz * TW;

    int tid  = threadIdx.x;
    int lane = tid & 63;
    int w    = tid >> 6;             // wave id, owns z-layers {2w, 2w+1}
    int vxa  = ox + (lane & 7);
    int vya  = oy + (lane >> 3);
    int l0   = 2*w, l1 = 2*w + 1;

    float accA[C_OUT], accB[C_OUT];
    #pragma unroll
    for (int c = 0; c < C_OUT; ++c) { accA[c] = 0.0f; accB[c] = 0.0f; }

    unsigned e0 = offsets[t], e1 = alloc[t];
    for (unsigned base = e0; base < e1; base += CHUNK) {
        int n = min((unsigned)CHUNK, e1 - base);
        if (tid < CHUNK) {
            if (tid < n) {
                unsigned p = entries[base + tid];
                float4 f = pf[p];
                unsigned key = __float_as_uint(f.w);
                int X = (int)(key & 511u) - 256;
                int Y = (int)((key >> 9) & 511u) - 256;
                int Z = (int)((key >> 18) & 511u) - 256;
                int cx0 = clampi(X, GW-1),  cx1 = clampi(X+1, GW-1);
                int cy0 = clampi(Y, GH-1),  cy1 = clampi(Y+1, GH-1);
                int cz0 = clampi(Z, GD-1),  cz1 = clampi(Z+1, GD-1);
                unsigned pk = (unsigned)cx0 | ((unsigned)cx1 << 8)
                            | ((unsigned)cy0 << 16) | ((unsigned)cy1 << 24);
                int st0 = ((unsigned)(cz0 - oz) < 8u) ? (cz0 - oz) : 255;
                int st1 = ((unsigned)(cz1 - oz) < 8u) ? (cz1 - oz) : 255;
                sA[tid] = make_float4(f.x, f.y, f.z, __uint_as_float(pk));
                sZ[tid] = st0 | (st1 << 8);
                #pragma unroll
                for (int q = 0; q < 4; ++q)
                    sO[q*CHUNK + tid] = po[(size_t)q * M_PTS + p];
            } else {
                sZ[tid] = 255 | (255 << 8);   // sentinel: hits no wave
            }
        }
        __syncthreads();

        const int4* sZ4 = (const int4*)sZ;
        int n4 = (n + 3) & ~3;
        for (int jb = 0; jb < n4; jb += 4) {
            int4 z4 = sZ4[jb >> 2];                     // broadcast batch of 4
            #pragma unroll
            for (int k = 0; k < 4; ++k) {
                int zz  = (k==0) ? z4.x : (k==1) ? z4.y : (k==2) ? z4.z : z4.w;
                int st0 = zz & 255, st1 = (zz >> 8) & 255;
                bool hitA = (st0 == l0) | (st1 == l0);   // wave-uniform
                bool hitB = (st0 == l1) | (st1 == l1);   // wave-uniform
                if (!(hitA | hitB)) continue;            // uniform skip
                int j = jb + k;
                float4 a = sA[j];
                unsigned pk = __float_as_uint(a.w);
                int cx0 = (int)(pk & 255u),         cx1 = (int)((pk >> 8) & 255u);
                int cy0 = (int)((pk >> 16) & 255u), cy1 = (int)(pk >> 24);

                float wx = ((vxa == cx0) ? 1.0f - a.x : 0.0f)
                         + ((vxa == cx1) ? a.x        : 0.0f);
                float wy = ((vya == cy0) ? 1.0f - a.y : 0.0f)
                         + ((vya == cy1) ? a.y        : 0.0f);
                float wxy = wx * wy;

                if (hitA) {
                    float wzA = ((st0 == l0) ? 1.0f - a.z : 0.0f)
                              + ((st1 == l0) ? a.z        : 0.0f);
                    float wA = wxy * wzA;
                    #pragma unroll
                    for (int q = 0; q < 4; ++q) {
                        float4 ov = sO[q*CHUNK + j];
                        accA[4*q+0] = fmaf(wA, ov.x, accA[4*q+0]);
                        accA[4*q+1] = fmaf(wA, ov.y, accA[4*q+1]);
                        accA[4*q+2] = fmaf(wA, ov.z, accA[4*q+2]);
                        accA[4*q+3] = fmaf(wA, ov.w, accA[4*q+3]);
                    }
                }
                if (hitB) {
                    float wzB = ((st0 == l1) ? 1.0f - a.z : 0.0f)
                              + ((st1 == l1) ? a.z        : 0.0f);
                    float wB = wxy * wzB;
                    #pragma unroll
                    for (int q = 0; q < 4; ++q) {
                        float4 ov = sO[q*CHUNK + j];
                        accB[4*q+0] = fmaf(wB, ov.x, accB[4*q+0]);
                        accB[4*q+1] = fmaf(wB, ov.y, accB[4*q+1]);
                        accB[4*q+2] = fmaf(wB, ov.z, accB[4*q+2]);
                        accB[4*q+3] = fmaf(wB, ov.w, accB[4*q+3]);
                    }
                }
            }
        }
        __syncthreads();
    }

    // ---- dense register writeback (full coverage -> no memset needed) ----
    size_t baseA = ((((size_t)(oz + l0)) * GH + vya) * GW + vxa) * C_OUT;
    size_t baseB = ((((size_t)(oz + l1)) * GH + vya) * GW + vxa) * C_OUT;
    #pragma unroll
    for (int q = 0; q < 4; ++q) {
        *(float4*)(out + baseA + 4*q) = make_float4(accA[4*q+0], accA[4*q+1], accA[4*q+2], accA[4*q+3]);
        *(float4*)(out + baseB + 4*q) = make_float4(accB[4*q+0], accB[4*q+1], accB[4*q+2], accB[4*q+3]);
    }
}

// ============================================================================
// Fallback (round-3 fused kernel) if workspace is too small.
// ============================================================================
#define SEGS   8
#define SEGLEN (NSAMP / SEGS)
#define NTHREADS (N_RAYS * SEGS)

__global__ __launch_bounds__(256, 2) void splat_seg_kernel(
    const float* __restrict__ origins, const float* __restrict__ dirs,
    const float* __restrict__ nearv,   const float* __restrict__ farv,
    const float* __restrict__ enc,     const int*   __restrict__ gidx,
    const float* __restrict__ grid,    const float* __restrict__ W0,
    const float* __restrict__ b0,      const float* __restrict__ W1,
    const float* __restrict__ b1,      float* __restrict__ out)
{
    int tid = blockIdx.x * blockDim.x + threadIdx.x;
    if (tid >= NTHREADS) return;
    int ray = tid / SEGS;
    int seg = tid - ray * SEGS;
    float nr = nearv[ray], fr = farv[ray];
    float ox = origins[3*ray+0], oy = origins[3*ray+1], oz = origins[3*ray+2];
    float rdx = dirs[3*ray+0],   rdy = dirs[3*ray+1],   rdz = dirs[3*ray+2];
    int   b  = gidx[ray];
    float accv[8][C_OUT];
    #pragma unroll
    for (int sl = 0; sl < 8; ++sl)
        #pragma unroll
        for (int c = 0; c < C_OUT; ++c) accv[sl][c] = 0.0f;
    int Xp = 0, Yp = 0, Zp = 0;
    #pragma unroll 1
    for (int k = 0; k < SEGLEN; ++k) {
        int s = seg * SEGLEN + k;
        float t  = nr + (fr - nr) * ((float)s * (1.0f / (NSAMP - 1)));
        float px = fmaf(t, rdx, ox);
        float py = fmaf(t, rdy, oy);
        float pz = fmaf(t, rdz, oz);
        float cx = ((px + 1.0f) * (float)GW - 1.0f) * 0.5f;
        float cy = ((py + 1.0f) * (float)GH - 1.0f) * 0.5f;
        float cz = ((pz + 1.0f) * (float)GD - 1.0f) * 0.5f;
        float fxf = floorf(cx), fyf = floorf(cy), fzf = floorf(cz);
        float fx = cx - fxf, fy = cy - fyf, fz = cz - fzf;
        int X = (int)fxf, Y = (int)fyf, Z = (int)fzf;
        if (k == 0) { Xp = X; Yp = Y; Zp = Z; }
        else if (X != Xp || Y != Yp || Z != Zp) {
            bool fXm[2], fYm[2], fZm[2];
            int  vx[2], vy[2], vz[2];
            #pragma unroll
            for (int p = 0; p < 2; ++p) {
                int xo = Xp + ((Xp ^ p) & 1), xn = X + ((X ^ p) & 1);
                fXm[p] = (xo != xn);  vx[p] = clampi(xo, GW-1);
                int yo = Yp + ((Yp ^ p) & 1), yn = Y + ((Y ^ p) & 1);
                fYm[p] = (yo != yn);  vy[p] = clampi(yo, GH-1);
                int zo = Zp + ((Zp ^ p) & 1), zn = Z + ((Z ^ p) & 1);
                fZm[p] = (zo != zn);  vz[p] = clampi(zo, GD-1);
            }
            #pragma unroll
            for (int pxi = 0; pxi < 2; ++pxi)
            #pragma unroll
            for (int pyi = 0; pyi < 2; ++pyi)
            #pragma unroll
            for (int pzi = 0; pzi < 2; ++pzi) {
                const int sl = pxi*4 + pyi*2 + pzi;
                if (fXm[pxi] | fYm[pyi] | fZm[pzi]) {
                    size_t flat = ((((size_t)b * GD + vz[pzi]) * GH + vy[pyi]) * GW + vx[pxi]) * C_OUT;
                    float* op = out + flat;
                    #pragma unroll
                    for (int c = 0; c < C_OUT; ++c) { atomicAdd(op + c, accv[sl][c]); accv[sl][c] = 0.0f; }
                }
            }
            Xp = X; Yp = Y; Zp = Z;
        }
        float feat[C_IN];
        {
            const float4* e4 = (const float4*)(enc + (size_t)ray * C_IN);
            #pragma unroll
            for (int q = 0; q < C_IN/4; ++q) {
                float4 v = e4[q];
                feat[4*q+0] = v.x; feat[4*q+1] = v.y; feat[4*q+2] = v.z; feat[4*q+3] = v.w;
            }
        }
        int gx[2] = { clampi(X, GW-1), clampi(X+1, GW-1) };
        int gy[2] = { clampi(Y, GH-1), clampi(Y+1, GH-1) };
        int gz[2] = { clampi(Z, GD-1), clampi(Z+1, GD-1) };
        float wxa[2] = { 1.0f - fx, fx };
        float wya[2] = { 1.0f - fy, fy };
        float wza[2] = { 1.0f - fz, fz };
        #pragma unroll
        for (int dz = 0; dz < 2; ++dz)
        #pragma unroll
        for (int dy = 0; dy < 2; ++dy)
        #pragma unroll
        for (int dx = 0; dx < 2; ++dx) {
            float w = wza[dz] * wya[dy] * wxa[dx];
            size_t flat = ((((size_t)b * GD + gz[dz]) * GH + gy[dy]) * GW + gx[dx]) * C_IN;
            const float4* g4 = (const float4*)(grid + flat);
            #pragma unroll
            for (int q = 0; q < C_IN/4; ++q) {
                float4 v = g4[q];
                feat[4*q+0] = fmaf(w, v.x, feat[4*q+0]);
                feat[4*q+1] = fmaf(w, v.y, feat[4*q+1]);
                feat[4*q+2] = fmaf(w, v.z, feat[4*q+2]);
                feat[4*q+3] = fmaf(w, v.w, feat[4*q+3]);
            }
        }
        float h[C_HID];
        #pragma unroll
        for (int j = 0; j < C_HID; ++j) h[j] = b0[j];
        #pragma unroll
        for (int i = 0; i < C_IN; ++i) {
            float xi = feat[i];
            #pragma unroll
            for (int j = 0; j < C_HID; ++j) h[j] = fmaf(xi, W0[i*C_HID + j], h[j]);
        }
        #pragma unroll
        for (int j = 0; j < C_HID; ++j) h[j] = fmaxf(h[j], 0.0f);
        float o[C_OUT];
        #pragma unroll
        for (int j = 0; j < C_OUT; ++j) o[j] = b1[j];
        #pragma unroll
        for (int i = 0; i < C_HID; ++i) {
            float hi = h[i];
            #pragma unroll
            for (int j = 0; j < C_OUT; ++j) o[j] = fmaf(hi, W1[i*C_OUT + j], o[j]);
        }
        float wxs[2], wys[2], wzs[2];
        #pragma unroll
        for (int p = 0; p < 2; ++p) {
            wxs[p] = ((X & 1) == p) ? (1.0f - fx) : fx;
            wys[p] = ((Y & 1) == p) ? (1.0f - fy) : fy;
            wzs[p] = ((Z & 1) == p) ? (1.0f - fz) : fz;
        }
        #pragma unroll
        for (int pxi = 0; pxi < 2; ++pxi)
        #pragma unroll
        for (int pyi = 0; pyi < 2; ++pyi)
        #pragma unroll
        for (int pzi = 0; pzi < 2; ++pzi) {
            const int sl = pxi*4 + pyi*2 + pzi;
            float w = wxs[pxi] * wys[pyi] * wzs[pzi];
            #pragma unroll
            for (int c = 0; c < C_OUT; ++c) accv[sl][c] = fmaf(w, o[c], accv[sl][c]);
        }
    }
    #pragma unroll
    for (int pxi = 0; pxi < 2; ++pxi)
    #pragma unroll
    for (int pyi = 0; pyi < 2; ++pyi)
    #pragma unroll
    for (int pzi = 0; pzi < 2; ++pzi) {
        const int sl = pxi*4 + pyi*2 + pzi;
        int vx = clampi(Xp + ((Xp ^ pxi) & 1), GW-1);
        int vy = clampi(Yp + ((Yp ^ pyi) & 1), GH-1);
        int vz = clampi(Zp + ((Zp ^ pzi) & 1), GD-1);
        size_t flat = ((((size_t)b * GD + vz) * GH + vy) * GW + vx) * C_OUT;
        float* op = out + flat;
        #pragma unroll
        for (int c = 0; c < C_OUT; ++c) atomicAdd(op + c, accv[sl][c]);
    }
}

// ============================================================================
extern "C" void kernel_launch(void* const* d_in, const int* in_sizes, int n_in,
                              void* d_out, int out_size, void* d_ws, size_t ws_size,
                              hipStream_t stream) {
    const float* origins = (const float*)d_in[0];
    const float* dirs    = (const float*)d_in[1];
    const float* nearv   = (const float*)d_in[2];
    const float* farv    = (const float*)d_in[3];
    const float* enc     = (const float*)d_in[4];
    const int*   gidx    = (const int*)  d_in[5];
    const float* grid    = (const float*)d_in[6];
    const float* W0      = (const float*)d_in[7];
    const float* b0      = (const float*)d_in[8];
    const float* W1      = (const float*)d_in[9];
    const float* b1      = (const float*)d_in[10];
    float* out = (float*)d_out;

    const size_t PF_B = (size_t)M_PTS * 16;         // 25,165,824
    const size_t PO_B = (size_t)M_PTS * 64;         // 100,663,296
    const size_t EN_B = (size_t)M_PTS * 8 * 4;      // 50,331,648 (hard bound)
    const size_t CT_B = (size_t)NTILES * 4;
    const size_t NEED = PF_B + PO_B + EN_B + 4 * CT_B;

    if (ws_size < NEED) {
        // fallback: fused register-merged scatter (round-3 path)
        hipMemsetAsync(out, 0, (size_t)out_size * sizeof(float), stream);
        splat_seg_kernel<<<NTHREADS/256, 256, 0, stream>>>(
            origins, dirs, nearv, farv, enc, gidx, grid, W0, b0, W1, b1, out);
        return;
    }

    char* w = (char*)d_ws;
    float4*   pf      = (float4*)   w;              w += PF_B;
    float4*   po      = (float4*)   w;              w += PO_B;
    unsigned* entries = (unsigned*) w;              w += EN_B;
    unsigned* counts  = (unsigned*) w;              w += CT_B;
    unsigned* offsets = (unsigned*) w;              w += CT_B;
    unsigned* alloc   = (unsigned*) w;              w += CT_B;
    unsigned* order   = (unsigned*) w;              w += CT_B;

    hipMemsetAsync(counts, 0, CT_B, stream);
    k1_point<<<M_PTS/256, 256, 0, stream>>>(origins, dirs, nearv, farv, enc, gidx,
                                            grid, W0, b0, W1, b1, pf, po, counts);
    k2_scan<<<1, 256, 0, stream>>>(counts, offsets, alloc, order);
    k3_scatter<<<M_PTS/256, 256, 0, stream>>>(pf, alloc, entries);
    k4_accum<<<NTILES, 256, 0, stream>>>(pf, po, entries, offsets, alloc, order, out);
    // K4 writes every output voxel densely -> no output memset needed.
}

// Round 15
// 450.301 us; speedup vs baseline: 1.5707x; 1.1370x over previous
//
#include <hip/hip_runtime.h>

#define N_RAYS 16384
#define NSAMP  96
#define GD 128
#define GH 128
#define GW 128
#define C_IN  32
#define C_HID 32
#define C_OUT 16
#define M_PTS (N_RAYS * NSAMP)       // 1,572,864 (divisible by 256)
#define TPA 16                        // tiles per axis (128/8)
#define NTILES (TPA*TPA*TPA)          // 4096
#define TW 8                          // tile width (voxels)
#define TVOX (TW*TW*TW)               // 512 voxels per tile
#define CHUNK 256                     // entries staged per K4 inner pass

__device__ __forceinline__ int clampi(int v, int hi) { return min(max(v, 0), hi); }

struct TileSpan { int txa, txb, tya, tyb, tza, tzb; };
__device__ __forceinline__ TileSpan tile_span(int X, int Y, int Z) {
    TileSpan s;
    s.txa = clampi(X,   GW-1) >> 3;  s.txb = clampi(X+1, GW-1) >> 3;
    s.tya = clampi(Y,   GH-1) >> 3;  s.tyb = clampi(Y+1, GH-1) >> 3;
    s.tza = clampi(Z,   GD-1) >> 3;  s.tzb = clampi(Z+1, GD-1) >> 3;
    return s;
}

// ============================================================================
// K1 v3 (r14, unchanged): wave-cooperative coalesced gather + MLP.
// ============================================================================
__global__ __launch_bounds__(256) void k1_point(
    const float* __restrict__ origins, const float* __restrict__ dirs,
    const float* __restrict__ nearv,   const float* __restrict__ farv,
    const float* __restrict__ enc,     const int*   __restrict__ gidx,
    const float* __restrict__ grid,    const float* __restrict__ W0,
    const float* __restrict__ b0,      const float* __restrict__ W1,
    const float* __restrict__ b1,
    float4* __restrict__ pf, float4* __restrict__ po, unsigned* __restrict__ counts)
{
    __shared__ __attribute__((aligned(16))) char smem[49152];
    uint2*    sOffW = (uint2*)smem;              // [256][8], 16 KB (dead after B)
    float4*   sFeat = (float4*)(smem + 16384);   // [256][8], 32 KB
    unsigned* lcnt  = (unsigned*)smem;           // 16 KB, reuses sOffW region

    int tid = threadIdx.x;
    int pid = blockIdx.x * 256 + tid;            // always < M_PTS (exact grid)
    int ray = pid / NSAMP;
    int s   = pid - ray * NSAMP;

    float nr = nearv[ray], fr = farv[ray];
    float t  = nr + (fr - nr) * ((float)s * (1.0f / (NSAMP - 1)));
    float px = fmaf(t, dirs[ray*3+0], origins[ray*3+0]);
    float py = fmaf(t, dirs[ray*3+1], origins[ray*3+1]);
    float pz = fmaf(t, dirs[ray*3+2], origins[ray*3+2]);
    int   b  = gidx[ray];

    float cx = ((px + 1.0f) * (float)GW - 1.0f) * 0.5f;
    float cy = ((py + 1.0f) * (float)GH - 1.0f) * 0.5f;
    float cz = ((pz + 1.0f) * (float)GD - 1.0f) * 0.5f;
    float fxf = floorf(cx), fyf = floorf(cy), fzf = floorf(cz);
    float fx = cx - fxf, fy = cy - fyf, fz = cz - fzf;
    int X = (int)fxf, Y = (int)fyf, Z = (int)fzf;

    int gx[2] = { clampi(X, GW-1), clampi(X+1, GW-1) };
    int gy[2] = { clampi(Y, GH-1), clampi(Y+1, GH-1) };
    int gz[2] = { clampi(Z, GD-1), clampi(Z+1, GD-1) };
    float wxa[2] = { 1.0f - fx, fx };
    float wya[2] = { 1.0f - fy, fy };
    float wza[2] = { 1.0f - fz, fz };

    #pragma unroll
    for (int dz = 0; dz < 2; ++dz)
    #pragma unroll
    for (int dy = 0; dy < 2; ++dy)
    #pragma unroll
    for (int dx = 0; dx < 2; ++dx) {
        const int ci = dz*4 + dy*2 + dx;
        unsigned flat = ((((unsigned)b * GD + gz[dz]) * GH + gy[dy]) * GW + gx[dx]) * C_IN;
        float w = wza[dz] * wya[dy] * wxa[dx];
        sOffW[tid*8 + ci] = make_uint2(flat, __float_as_uint(w));
    }
    __syncthreads();

    int lane  = tid & 63;
    int wbase = tid & ~63;
    int sub   = lane >> 3;
    int q     = lane & 7;
    #pragma unroll
    for (int g = 0; g < 8; ++g) {
        int p = wbase + g*8 + sub;
        float4 acc = make_float4(0.0f, 0.0f, 0.0f, 0.0f);
        #pragma unroll
        for (int c = 0; c < 8; ++c) {
            uint2 ow = sOffW[p*8 + c];
            const float4* src = (const float4*)(grid + ow.x);
            float4 v = src[q];
            float wgt = __uint_as_float(ow.y);
            acc.x = fmaf(wgt, v.x, acc.x);
            acc.y = fmaf(wgt, v.y, acc.y);
            acc.z = fmaf(wgt, v.z, acc.z);
            acc.w = fmaf(wgt, v.w, acc.w);
        }
        sFeat[p*8 + ((q + p) & 7)] = acc;
    }
    __syncthreads();

    float feat[C_IN];
    {
        const float4* e4 = (const float4*)(enc + (size_t)ray * C_IN);
        #pragma unroll
        for (int qq = 0; qq < 8; ++qq) {
            float4 fv = sFeat[tid*8 + ((qq + tid) & 7)];
            float4 ev = e4[qq];
            feat[4*qq+0] = fv.x + ev.x;
            feat[4*qq+1] = fv.y + ev.y;
            feat[4*qq+2] = fv.z + ev.z;
            feat[4*qq+3] = fv.w + ev.w;
        }
    }
    for (int i = tid; i < NTILES; i += 256) lcnt[i] = 0;

    float h[C_HID];
    #pragma unroll
    for (int j = 0; j < C_HID; ++j) h[j] = b0[j];
    #pragma unroll
    for (int i = 0; i < C_IN; ++i) {
        float xi = feat[i];
        #pragma unroll
        for (int j = 0; j < C_HID; ++j) h[j] = fmaf(xi, W0[i*C_HID + j], h[j]);
    }
    #pragma unroll
    for (int j = 0; j < C_HID; ++j) h[j] = fmaxf(h[j], 0.0f);

    float o[C_OUT];
    #pragma unroll
    for (int j = 0; j < C_OUT; ++j) o[j] = b1[j];
    #pragma unroll
    for (int i = 0; i < C_HID; ++i) {
        float hi = h[i];
        #pragma unroll
        for (int j = 0; j < C_OUT; ++j) o[j] = fmaf(hi, W1[i*C_OUT + j], o[j]);
    }

    unsigned key = ((unsigned)(X + 256) & 511u)
                 | (((unsigned)(Y + 256) & 511u) << 9)
                 | (((unsigned)(Z + 256) & 511u) << 18);
    pf[pid] = make_float4(fx, fy, fz, __uint_as_float(key));
    #pragma unroll
    for (int qq = 0; qq < 4; ++qq)
        po[(size_t)qq * M_PTS + pid] = make_float4(o[4*qq+0], o[4*qq+1], o[4*qq+2], o[4*qq+3]);

    __syncthreads();
    TileSpan ts = tile_span(X, Y, Z);
    #pragma unroll
    for (int ez = 0; ez < 2; ++ez) {
        if (ez && ts.tzb == ts.tza) continue;
        #pragma unroll
        for (int ey = 0; ey < 2; ++ey) {
            if (ey && ts.tyb == ts.tya) continue;
            #pragma unroll
            for (int ex = 0; ex < 2; ++ex) {
                if (ex && ts.txb == ts.txa) continue;
                int tt = ((ts.tza + ez) * TPA + (ts.tya + ey)) * TPA + (ts.txa + ex);
                atomicAdd(&lcnt[tt], 1u);
            }
        }
    }
    __syncthreads();
    for (int i = tid; i < NTILES; i += 256)
        if (lcnt[i]) atomicAdd(&counts[i], lcnt[i]);
}

// ============================================================================
// K2 v2: PARALLEL scans (shuffle prefix-sums) -- the two tid0-serial 256-iter
// LDS chains (~50 us of pure latency) become ~8 us. Same outputs.
// ============================================================================
__global__ __launch_bounds__(256) void k2_scan(
    const unsigned* __restrict__ counts,
    unsigned* __restrict__ offsets, unsigned* __restrict__ alloc,
    unsigned* __restrict__ order)
{
    __shared__ unsigned wsum[4], wbase[4];
    __shared__ unsigned bwsum[4], bwbase[4];
    __shared__ unsigned bh[256];
    __shared__ unsigned bb[256];
    int tid = threadIdx.x, lane = tid & 63, wv = tid >> 6;
    unsigned base = tid * 16;
    unsigned loc[16];
    unsigned ssum = 0;
    #pragma unroll
    for (int i = 0; i < 16; ++i) { loc[i] = counts[base + i]; ssum += loc[i]; }
    bh[tid] = 0;

    // inclusive scan of per-thread sums (wave shuffle + tiny cross-wave fix)
    unsigned x = ssum;
    #pragma unroll
    for (int d = 1; d < 64; d <<= 1) {
        unsigned v = __shfl_up(x, d);
        if (lane >= d) x += v;
    }
    if (lane == 63) wsum[wv] = x;
    __syncthreads();
    if (tid == 0) { unsigned r = 0; for (int ww = 0; ww < 4; ++ww) { wbase[ww] = r; r += wsum[ww]; } }
    __syncthreads();
    unsigned run = wbase[wv] + x - ssum;      // exclusive prefix
    #pragma unroll
    for (int i = 0; i < 16; ++i) {
        unsigned v = loc[i];
        offsets[base + i] = run;
        alloc[base + i]   = run;
        run += v;
        atomicAdd(&bh[min(v >> 4, 255u)], 1u);
    }
    __syncthreads();

    // heavy-first schedule: exclusive scan of bh in DESCENDING bucket order
    unsigned hv = bh[255 - tid];
    unsigned y = hv;
    #pragma unroll
    for (int d = 1; d < 64; d <<= 1) {
        unsigned v = __shfl_up(y, d);
        if (lane >= d) y += v;
    }
    if (lane == 63) bwsum[wv] = y;
    __syncthreads();
    if (tid == 0) { unsigned r = 0; for (int ww = 0; ww < 4; ++ww) { bwbase[ww] = r; r += bwsum[ww]; } }
    __syncthreads();
    bb[255 - tid] = bwbase[wv] + y - hv;
    __syncthreads();
    #pragma unroll
    for (int i = 0; i < 16; ++i) {
        unsigned v = loc[i];
        unsigned slot = atomicAdd(&bb[min(v >> 4, 255u)], 1u);
        order[slot] = base + i;
    }
}

// ============================================================================
// K3: scatter point indices into per-tile segments (unchanged).
// ============================================================================
__global__ __launch_bounds__(256) void k3_scatter(
    const float4* __restrict__ pf, unsigned* __restrict__ alloc,
    unsigned* __restrict__ entries)
{
    __shared__ unsigned lcnt[NTILES];
    __shared__ unsigned lbase[NTILES];
    for (int i = threadIdx.x; i < NTILES; i += 256) lcnt[i] = 0;
    __syncthreads();

    int pid = blockIdx.x * 256 + threadIdx.x;
    float4 f = pf[pid];
    unsigned key = __float_as_uint(f.w);
    int X = (int)(key & 511u) - 256;
    int Y = (int)((key >> 9) & 511u) - 256;
    int Z = (int)((key >> 18) & 511u) - 256;
    TileSpan ts = tile_span(X, Y, Z);

    unsigned rnk[2][2][2];
    #pragma unroll
    for (int ez = 0; ez < 2; ++ez) {
        bool okz = (ez == 0) || (ts.tzb > ts.tza);
        #pragma unroll
        for (int ey = 0; ey < 2; ++ey) {
            bool oky = (ey == 0) || (ts.tyb > ts.tya);
            #pragma unroll
            for (int ex = 0; ex < 2; ++ex) {
                bool okx = (ex == 0) || (ts.txb > ts.txa);
                if (okz && oky && okx) {
                    int tt = ((ts.tza + ez) * TPA + (ts.tya + ey)) * TPA + (ts.txa + ex);
                    rnk[ez][ey][ex] = atomicAdd(&lcnt[tt], 1u);
                }
            }
        }
    }
    __syncthreads();
    for (int i = threadIdx.x; i < NTILES; i += 256)
        if (lcnt[i]) lbase[i] = atomicAdd(&alloc[i], lcnt[i]);
    __syncthreads();
    #pragma unroll
    for (int ez = 0; ez < 2; ++ez) {
        bool okz = (ez == 0) || (ts.tzb > ts.tza);
        #pragma unroll
        for (int ey = 0; ey < 2; ++ey) {
            bool oky = (ey == 0) || (ts.tyb > ts.tya);
            #pragma unroll
            for (int ex = 0; ex < 2; ++ex) {
                bool okx = (ex == 0) || (ts.txb > ts.txa);
                if (okz && oky && okx) {
                    int tt = ((ts.tza + ez) * TPA + (ts.tya + ey)) * TPA + (ts.txa + ex);
                    entries[lbase[tt] + rnk[ez][ey][ex]] = (unsigned)pid;
                }
            }
        }
    }
}

// ============================================================================
// K4 v3: register accumulation + BALLOT-BUILT per-wave hit lists.
// Staging (all 256 threads, CHUNK=256): each wave __ballot-s "does entry hit
// target wave tw" for tw=0..3 -> 16 uint64 masks in LDS. Splat phase walks
// set bits only (ctzll), eliminating the 4-wave full-chunk scan (~25 wave-
// instrs/entry -> ~5/hit). Heavy-first order + per-layer guards kept.
// ============================================================================
__global__ __launch_bounds__(256) void k4_accum(
    const float4* __restrict__ pf, const float4* __restrict__ po,
    const unsigned* __restrict__ entries, const unsigned* __restrict__ offsets,
    const unsigned* __restrict__ alloc, const unsigned* __restrict__ order,
    float* __restrict__ out)
{
    __shared__ __attribute__((aligned(16))) float4 sA[CHUNK];   // fx,fy,fz, cx0|cx1|cy0|cy1
    __shared__ __attribute__((aligned(16))) int    sZ[CHUNK];   // st0|st1<<8 (255=out)
    __shared__ __attribute__((aligned(16))) float4 sO[4*CHUNK]; // o[16] planar [q][entry]
    __shared__ unsigned long long sMask[4][4];                  // [target wave][group]

    int t  = order[blockIdx.x];      // heavy tiles scheduled first
    int tx = t & (TPA-1), ty = (t >> 4) & (TPA-1), tz = t >> 8;
    int ox = tx * TW, oy = ty * TW, oz = tz * TW;

    int tid  = threadIdx.x;
    int lane = tid & 63;
    int w    = tid >> 6;             // wave id, owns z-layers {2w, 2w+1}
    int vxa  = ox + (lane & 7);
    int vya  = oy + (lane >> 3);
    int l0   = 2*w, l1 = 2*w + 1;

    float accA[C_OUT], accB[C_OUT];
    #pragma unroll
    for (int c = 0; c < C_OUT; ++c) { accA[c] = 0.0f; accB[c] = 0.0f; }

    unsigned e0 = offsets[t], e1 = alloc[t];
    for (unsigned base = e0; base < e1; base += CHUNK) {
        int n = min((unsigned)CHUNK, e1 - base);
        int st0 = 255, st1 = 255;
        if (tid < n) {
            unsigned p = entries[base + tid];
            float4 f = pf[p];
            unsigned key = __float_as_uint(f.w);
            int X = (int)(key & 511u) - 256;
            int Y = (int)((key >> 9) & 511u) - 256;
            int Z = (int)((key >> 18) & 511u) - 256;
            int cx0 = clampi(X, GW-1),  cx1 = clampi(X+1, GW-1);
            int cy0 = clampi(Y, GH-1),  cy1 = clampi(Y+1, GH-1);
            int cz0 = clampi(Z, GD-1),  cz1 = clampi(Z+1, GD-1);
            unsigned pk = (unsigned)cx0 | ((unsigned)cx1 << 8)
                        | ((unsigned)cy0 << 16) | ((unsigned)cy1 << 24);
            st0 = ((unsigned)(cz0 - oz) < 8u) ? (cz0 - oz) : 255;
            st1 = ((unsigned)(cz1 - oz) < 8u) ? (cz1 - oz) : 255;
            sA[tid] = make_float4(f.x, f.y, f.z, __uint_as_float(pk));
            sZ[tid] = st0 | (st1 << 8);
            #pragma unroll
            for (int q = 0; q < 4; ++q)
                sO[q*CHUNK + tid] = po[(size_t)q * M_PTS + p];
        }
        int w0 = st0 >> 1, w1 = st1 >> 1;
        #pragma unroll
        for (int tw = 0; tw < 4; ++tw) {
            unsigned long long m = __ballot((w0 == tw) | (w1 == tw));
            if (lane == 0) sMask[tw][tid >> 6] = m;
        }
        __syncthreads();

        #pragma unroll
        for (int g = 0; g < 4; ++g) {
            unsigned long long m = sMask[w][g];      // wave-uniform
            while (m) {
                int j = (g << 6) + (int)__builtin_ctzll(m);
                m &= m - 1;
                float4 a = sA[j];
                int zz = sZ[j];
                int s0 = zz & 255, s1 = (zz >> 8) & 255;
                unsigned pk = __float_as_uint(a.w);
                int cx0 = (int)(pk & 255u),         cx1 = (int)((pk >> 8) & 255u);
                int cy0 = (int)((pk >> 16) & 255u), cy1 = (int)(pk >> 24);

                float wx = ((vxa == cx0) ? 1.0f - a.x : 0.0f)
                         + ((vxa == cx1) ? a.x        : 0.0f);
                float wy = ((vya == cy0) ? 1.0f - a.y : 0.0f)
                         + ((vya == cy1) ? a.y        : 0.0f);
                float wxy = wx * wy;

                bool hitA = (s0 == l0) | (s1 == l0);   // wave-uniform
                if (hitA) {
                    float wzA = ((s0 == l0) ? 1.0f - a.z : 0.0f)
                              + ((s1 == l0) ? a.z        : 0.0f);
                    float wA = wxy * wzA;
                    #pragma unroll
                    for (int q = 0; q < 4; ++q) {
                        float4 ov = sO[q*CHUNK + j];
                        accA[4*q+0] = fmaf(wA, ov.x, accA[4*q+0]);
                        accA[4*q+1] = fmaf(wA, ov.y, accA[4*q+1]);
                        accA[4*q+2] = fmaf(wA, ov.z, accA[4*q+2]);
                        accA[4*q+3] = fmaf(wA, ov.w, accA[4*q+3]);
                    }
                }
                bool hitB = (s0 == l1) | (s1 == l1);   // wave-uniform
                if (hitB) {
                    float wzB = ((s0 == l1) ? 1.0f - a.z : 0.0f)
                              + ((s1 == l1) ? a.z        : 0.0f);
                    float wB = wxy * wzB;
                    #pragma unroll
                    for (int q = 0; q < 4; ++q) {
                        float4 ov = sO[q*CHUNK + j];
                        accB[4*q+0] = fmaf(wB, ov.x, accB[4*q+0]);
                        accB[4*q+1] = fmaf(wB, ov.y, accB[4*q+1]);
                        accB[4*q+2] = fmaf(wB, ov.z, accB[4*q+2]);
                        accB[4*q+3] = fmaf(wB, ov.w, accB[4*q+3]);
                    }
                }
            }
        }
        __syncthreads();
    }

    // ---- dense register writeback (full coverage -> no memset needed) ----
    size_t baseA = ((((size_t)(oz + l0)) * GH + vya) * GW + vxa) * C_OUT;
    size_t baseB = ((((size_t)(oz + l1)) * GH + vya) * GW + vxa) * C_OUT;
    #pragma unroll
    for (int q = 0; q < 4; ++q) {
        *(float4*)(out + baseA + 4*q) = make_float4(accA[4*q+0], accA[4*q+1], accA[4*q+2], accA[4*q+3]);
        *(float4*)(out + baseB + 4*q) = make_float4(accB[4*q+0], accB[4*q+1], accB[4*q+2], accB[4*q+3]);
    }
}

// ============================================================================
// Fallback (round-3 fused kernel) if workspace is too small.
// ============================================================================
#define SEGS   8
#define SEGLEN (NSAMP / SEGS)
#define NTHREADS (N_RAYS * SEGS)

__global__ __launch_bounds__(256, 2) void splat_seg_kernel(
    const float* __restrict__ origins, const float* __restrict__ dirs,
    const float* __restrict__ nearv,   const float* __restrict__ farv,
    const float* __restrict__ enc,     const int*   __restrict__ gidx,
    const float* __restrict__ grid,    const float* __restrict__ W0,
    const float* __restrict__ b0,      const float* __restrict__ W1,
    const float* __restrict__ b1,      float* __restrict__ out)
{
    int tid = blockIdx.x * blockDim.x + threadIdx.x;
    if (tid >= NTHREADS) return;
    int ray = tid / SEGS;
    int seg = tid - ray * SEGS;
    float nr = nearv[ray], fr = farv[ray];
    float ox = origins[3*ray+0], oy = origins[3*ray+1], oz = origins[3*ray+2];
    float rdx = dirs[3*ray+0],   rdy = dirs[3*ray+1],   rdz = dirs[3*ray+2];
    int   b  = gidx[ray];
    float accv[8][C_OUT];
    #pragma unroll
    for (int sl = 0; sl < 8; ++sl)
        #pragma unroll
        for (int c = 0; c < C_OUT; ++c) accv[sl][c] = 0.0f;
    int Xp = 0, Yp = 0, Zp = 0;
    #pragma unroll 1
    for (int k = 0; k < SEGLEN; ++k) {
        int s = seg * SEGLEN + k;
        float t  = nr + (fr - nr) * ((float)s * (1.0f / (NSAMP - 1)));
        float px = fmaf(t, rdx, ox);
        float py = fmaf(t, rdy, oy);
        float pz = fmaf(t, rdz, oz);
        float cx = ((px + 1.0f) * (float)GW - 1.0f) * 0.5f;
        float cy = ((py + 1.0f) * (float)GH - 1.0f) * 0.5f;
        float cz = ((pz + 1.0f) * (float)GD - 1.0f) * 0.5f;
        float fxf = floorf(cx), fyf = floorf(cy), fzf = floorf(cz);
        float fx = cx - fxf, fy = cy - fyf, fz = cz - fzf;
        int X = (int)fxf, Y = (int)fyf, Z = (int)fzf;
        if (k == 0) { Xp = X; Yp = Y; Zp = Z; }
        else if (X != Xp || Y != Yp || Z != Zp) {
            bool fXm[2], fYm[2], fZm[2];
            int  vx[2], vy[2], vz[2];
            #pragma unroll
            for (int p = 0; p < 2; ++p) {
                int xo = Xp + ((Xp ^ p) & 1), xn = X + ((X ^ p) & 1);
                fXm[p] = (xo != xn);  vx[p] = clampi(xo, GW-1);
                int yo = Yp + ((Yp ^ p) & 1), yn = Y + ((Y ^ p) & 1);
                fYm[p] = (yo != yn);  vy[p] = clampi(yo, GH-1);
                int zo = Zp + ((Zp ^ p) & 1), zn = Z + ((Z ^ p) & 1);
                fZm[p] = (zo != zn);  vz[p] = clampi(zo, GD-1);
            }
            #pragma unroll
            for (int pxi = 0; pxi < 2; ++pxi)
            #pragma unroll
            for (int pyi = 0; pyi < 2; ++pyi)
            #pragma unroll
            for (int pzi = 0; pzi < 2; ++pzi) {
                const int sl = pxi*4 + pyi*2 + pzi;
                if (fXm[pxi] | fYm[pyi] | fZm[pzi]) {
                    size_t flat = ((((size_t)b * GD + vz[pzi]) * GH + vy[pyi]) * GW + vx[pxi]) * C_OUT;
                    float* op = out + flat;
                    #pragma unroll
                    for (int c = 0; c < C_OUT; ++c) { atomicAdd(op + c, accv[sl][c]); accv[sl][c] = 0.0f; }
                }
            }
            Xp = X; Yp = Y; Zp = Z;
        }
        float feat[C_IN];
        {
            const float4* e4 = (const float4*)(enc + (size_t)ray * C_IN);
            #pragma unroll
            for (int q = 0; q < C_IN/4; ++q) {
                float4 v = e4[q];
                feat[4*q+0] = v.x; feat[4*q+1] = v.y; feat[4*q+2] = v.z; feat[4*q+3] = v.w;
            }
        }
        int gx[2] = { clampi(X, GW-1), clampi(X+1, GW-1) };
        int gy[2] = { clampi(Y, GH-1), clampi(Y+1, GH-1) };
        int gz[2] = { clampi(Z, GD-1), clampi(Z+1, GD-1) };
        float wxa[2] = { 1.0f - fx, fx };
        float wya[2] = { 1.0f - fy, fy };
        float wza[2] = { 1.0f - fz, fz };
        #pragma unroll
        for (int dz = 0; dz < 2; ++dz)
        #pragma unroll
        for (int dy = 0; dy < 2; ++dy)
        #pragma unroll
        for (int dx = 0; dx < 2; ++dx) {
            float w = wza[dz] * wya[dy] * wxa[dx];
            size_t flat = ((((size_t)b * GD + gz[dz]) * GH + gy[dy]) * GW + gx[dx]) * C_IN;
            const float4* g4 = (const float4*)(grid + flat);
            #pragma unroll
            for (int q = 0; q < C_IN/4; ++q) {
                float4 v = g4[q];
                feat[4*q+0] = fmaf(w, v.x, feat[4*q+0]);
                feat[4*q+1] = fmaf(w, v.y, feat[4*q+1]);
                feat[4*q+2] = fmaf(w, v.z, feat[4*q+2]);
                feat[4*q+3] = fmaf(w, v.w, feat[4*q+3]);
            }
        }
        float h[C_HID];
        #pragma unroll
        for (int j = 0; j < C_HID; ++j) h[j] = b0[j];
        #pragma unroll
        for (int i = 0; i < C_IN; ++i) {
            float xi = feat[i];
            #pragma unroll
            for (int j = 0; j < C_HID; ++j) h[j] = fmaf(xi, W0[i*C_HID + j], h[j]);
        }
        #pragma unroll
        for (int j = 0; j < C_HID; ++j) h[j] = fmaxf(h[j], 0.0f);
        float o[C_OUT];
        #pragma unroll
        for (int j = 0; j < C_OUT; ++j) o[j] = b1[j];
        #pragma unroll
        for (int i = 0; i < C_HID; ++i) {
            float hi = h[i];
            #pragma unroll
            for (int j = 0; j < C_OUT; ++j) o[j] = fmaf(hi, W1[i*C_OUT + j], o[j]);
        }
        float wxs[2], wys[2], wzs[2];
        #pragma unroll
        for (int p = 0; p < 2; ++p) {
            wxs[p] = ((X & 1) == p) ? (1.0f - fx) : fx;
            wys[p] = ((Y & 1) == p) ? (1.0f - fy) : fy;
            wzs[p] = ((Z & 1) == p) ? (1.0f - fz) : fz;
        }
        #pragma unroll
        for (int pxi = 0; pxi < 2; ++pxi)
        #pragma unroll
        for (int pyi = 0; pyi < 2; ++pyi)
        #pragma unroll
        for (int pzi = 0; pzi < 2; ++pzi) {
            const int sl = pxi*4 + pyi*2 + pzi;
            float w = wxs[pxi] * wys[pyi] * wzs[pzi];
            #pragma unroll
            for (int c = 0; c < C_OUT; ++c) accv[sl][c] = fmaf(w, o[c], accv[sl][c]);
        }
    }
    #pragma unroll
    for (int pxi = 0; pxi < 2; ++pxi)
    #pragma unroll
    for (int pyi = 0; pyi < 2; ++pyi)
    #pragma unroll
    for (int pzi = 0; pzi < 2; ++pzi) {
        const int sl = pxi*4 + pyi*2 + pzi;
        int vx = clampi(Xp + ((Xp ^ pxi) & 1), GW-1);
        int vy = clampi(Yp + ((Yp ^ pyi) & 1), GH-1);
        int vz = clampi(Zp + ((Zp ^ pzi) & 1), GD-1);
        size_t flat = ((((size_t)b * GD + vz) * GH + vy) * GW + vx) * C_OUT;
        float* op = out + flat;
        #pragma unroll
        for (int c = 0; c < C_OUT; ++c) atomicAdd(op + c, accv[sl][c]);
    }
}

// ============================================================================
extern "C" void kernel_launch(void* const* d_in, const int* in_sizes, int n_in,
                              void* d_out, int out_size, void* d_ws, size_t ws_size,
                              hipStream_t stream) {
    const float* origins = (const float*)d_in[0];
    const float* dirs    = (const float*)d_in[1];
    const float* nearv   = (const float*)d_in[2];
    const float* farv    = (const float*)d_in[3];
    const float* enc     = (const float*)d_in[4];
    const int*   gidx    = (const int*)  d_in[5];
    const float* grid    = (const float*)d_in[6];
    const float* W0      = (const float*)d_in[7];
    const float* b0      = (const float*)d_in[8];
    const float* W1      = (const float*)d_in[9];
    const float* b1      = (const float*)d_in[10];
    float* out = (float*)d_out;

    const size_t PF_B = (size_t)M_PTS * 16;         // 25,165,824
    const size_t PO_B = (size_t)M_PTS * 64;         // 100,663,296
    const size_t EN_B = (size_t)M_PTS * 8 * 4;      // 50,331,648 (hard bound)
    const size_t CT_B = (size_t)NTILES * 4;
    const size_t NEED = PF_B + PO_B + EN_B + 4 * CT_B;

    if (ws_size < NEED) {
        // fallback: fused register-merged scatter (round-3 path)
        hipMemsetAsync(out, 0, (size_t)out_size * sizeof(float), stream);
        splat_seg_kernel<<<NTHREADS/256, 256, 0, stream>>>(
            origins, dirs, nearv, farv, enc, gidx, grid, W0, b0, W1, b1, out);
        return;
    }

    char* w = (char*)d_ws;
    float4*   pf      = (float4*)   w;              w += PF_B;
    float4*   po      = (float4*)   w;              w += PO_B;
    unsigned* entries = (unsigned*) w;              w += EN_B;
    unsigned* counts  = (unsigned*) w;              w += CT_B;
    unsigned* offsets = (unsigned*) w;              w += CT_B;
    unsigned* alloc   = (unsigned*) w;              w += CT_B;
    unsigned* order   = (unsigned*) w;              w += CT_B;

    hipMemsetAsync(counts, 0, CT_B, stream);
    k1_point<<<M_PTS/256, 256, 0, stream>>>(origins, dirs, nearv, farv, enc, gidx,
                                            grid, W0, b0, W1, b1, pf, po, counts);
    k2_scan<<<1, 256, 0, stream>>>(counts, offsets, alloc, order);
    k3_scatter<<<M_PTS/256, 256, 0, stream>>>(pf, alloc, entries);
    k4_accum<<<NTILES, 256, 0, stream>>>(pf, po, entries, offsets, alloc, order, out);
    // K4 writes every output voxel densely -> no output memset needed.
}

// Round 16
// 441.722 us; speedup vs baseline: 1.6012x; 1.0194x over previous
//
#include <hip/hip_runtime.h>

#define N_RAYS 16384
#define NSAMP  96
#define GD 128
#define GH 128
#define GW 128
#define C_IN  32
#define C_HID 32
#define C_OUT 16
#define M_PTS (N_RAYS * NSAMP)       // 1,572,864 (divisible by 256)
#define TPA 16                        // tiles per axis (128/8)
#define NTILES (TPA*TPA*TPA)          // 4096
#define TW 8                          // tile width (voxels)
#define TVOX (TW*TW*TW)               // 512 voxels per tile
#define CHUNK 256                     // entries staged per K4 inner pass

__device__ __forceinline__ int clampi(int v, int hi) { return min(max(v, 0), hi); }

struct TileSpan { int txa, txb, tya, tyb, tza, tzb; };
__device__ __forceinline__ TileSpan tile_span(int X, int Y, int Z) {
    TileSpan s;
    s.txa = clampi(X,   GW-1) >> 3;  s.txb = clampi(X+1, GW-1) >> 3;
    s.tya = clampi(Y,   GH-1) >> 3;  s.tyb = clampi(Y+1, GH-1) >> 3;
    s.tza = clampi(Z,   GD-1) >> 3;  s.tzb = clampi(Z+1, GD-1) >> 3;
    return s;
}

// ============================================================================
// K1 v3 (r14, unchanged): wave-cooperative coalesced gather + MLP.
// ============================================================================
__global__ __launch_bounds__(256) void k1_point(
    const float* __restrict__ origins, const float* __restrict__ dirs,
    const float* __restrict__ nearv,   const float* __restrict__ farv,
    const float* __restrict__ enc,     const int*   __restrict__ gidx,
    const float* __restrict__ grid,    const float* __restrict__ W0,
    const float* __restrict__ b0,      const float* __restrict__ W1,
    const float* __restrict__ b1,
    float4* __restrict__ pf, float4* __restrict__ po, unsigned* __restrict__ counts)
{
    __shared__ __attribute__((aligned(16))) char smem[49152];
    uint2*    sOffW = (uint2*)smem;              // [256][8], 16 KB (dead after B)
    float4*   sFeat = (float4*)(smem + 16384);   // [256][8], 32 KB
    unsigned* lcnt  = (unsigned*)smem;           // 16 KB, reuses sOffW region

    int tid = threadIdx.x;
    int pid = blockIdx.x * 256 + tid;            // always < M_PTS (exact grid)
    int ray = pid / NSAMP;
    int s   = pid - ray * NSAMP;

    float nr = nearv[ray], fr = farv[ray];
    float t  = nr + (fr - nr) * ((float)s * (1.0f / (NSAMP - 1)));
    float px = fmaf(t, dirs[ray*3+0], origins[ray*3+0]);
    float py = fmaf(t, dirs[ray*3+1], origins[ray*3+1]);
    float pz = fmaf(t, dirs[ray*3+2], origins[ray*3+2]);
    int   b  = gidx[ray];

    float cx = ((px + 1.0f) * (float)GW - 1.0f) * 0.5f;
    float cy = ((py + 1.0f) * (float)GH - 1.0f) * 0.5f;
    float cz = ((pz + 1.0f) * (float)GD - 1.0f) * 0.5f;
    float fxf = floorf(cx), fyf = floorf(cy), fzf = floorf(cz);
    float fx = cx - fxf, fy = cy - fyf, fz = cz - fzf;
    int X = (int)fxf, Y = (int)fyf, Z = (int)fzf;

    int gx[2] = { clampi(X, GW-1), clampi(X+1, GW-1) };
    int gy[2] = { clampi(Y, GH-1), clampi(Y+1, GH-1) };
    int gz[2] = { clampi(Z, GD-1), clampi(Z+1, GD-1) };
    float wxa[2] = { 1.0f - fx, fx };
    float wya[2] = { 1.0f - fy, fy };
    float wza[2] = { 1.0f - fz, fz };

    #pragma unroll
    for (int dz = 0; dz < 2; ++dz)
    #pragma unroll
    for (int dy = 0; dy < 2; ++dy)
    #pragma unroll
    for (int dx = 0; dx < 2; ++dx) {
        const int ci = dz*4 + dy*2 + dx;
        unsigned flat = ((((unsigned)b * GD + gz[dz]) * GH + gy[dy]) * GW + gx[dx]) * C_IN;
        float w = wza[dz] * wya[dy] * wxa[dx];
        sOffW[tid*8 + ci] = make_uint2(flat, __float_as_uint(w));
    }
    __syncthreads();

    int lane  = tid & 63;
    int wbase = tid & ~63;
    int sub   = lane >> 3;
    int q     = lane & 7;
    #pragma unroll
    for (int g = 0; g < 8; ++g) {
        int p = wbase + g*8 + sub;
        float4 acc = make_float4(0.0f, 0.0f, 0.0f, 0.0f);
        #pragma unroll
        for (int c = 0; c < 8; ++c) {
            uint2 ow = sOffW[p*8 + c];
            const float4* src = (const float4*)(grid + ow.x);
            float4 v = src[q];
            float wgt = __uint_as_float(ow.y);
            acc.x = fmaf(wgt, v.x, acc.x);
            acc.y = fmaf(wgt, v.y, acc.y);
            acc.z = fmaf(wgt, v.z, acc.z);
            acc.w = fmaf(wgt, v.w, acc.w);
        }
        sFeat[p*8 + ((q + p) & 7)] = acc;
    }
    __syncthreads();

    float feat[C_IN];
    {
        const float4* e4 = (const float4*)(enc + (size_t)ray * C_IN);
        #pragma unroll
        for (int qq = 0; qq < 8; ++qq) {
            float4 fv = sFeat[tid*8 + ((qq + tid) & 7)];
            float4 ev = e4[qq];
            feat[4*qq+0] = fv.x + ev.x;
            feat[4*qq+1] = fv.y + ev.y;
            feat[4*qq+2] = fv.z + ev.z;
            feat[4*qq+3] = fv.w + ev.w;
        }
    }
    for (int i = tid; i < NTILES; i += 256) lcnt[i] = 0;

    float h[C_HID];
    #pragma unroll
    for (int j = 0; j < C_HID; ++j) h[j] = b0[j];
    #pragma unroll
    for (int i = 0; i < C_IN; ++i) {
        float xi = feat[i];
        #pragma unroll
        for (int j = 0; j < C_HID; ++j) h[j] = fmaf(xi, W0[i*C_HID + j], h[j]);
    }
    #pragma unroll
    for (int j = 0; j < C_HID; ++j) h[j] = fmaxf(h[j], 0.0f);

    float o[C_OUT];
    #pragma unroll
    for (int j = 0; j < C_OUT; ++j) o[j] = b1[j];
    #pragma unroll
    for (int i = 0; i < C_HID; ++i) {
        float hi = h[i];
        #pragma unroll
        for (int j = 0; j < C_OUT; ++j) o[j] = fmaf(hi, W1[i*C_OUT + j], o[j]);
    }

    unsigned key = ((unsigned)(X + 256) & 511u)
                 | (((unsigned)(Y + 256) & 511u) << 9)
                 | (((unsigned)(Z + 256) & 511u) << 18);
    pf[pid] = make_float4(fx, fy, fz, __uint_as_float(key));
    #pragma unroll
    for (int qq = 0; qq < 4; ++qq)
        po[(size_t)qq * M_PTS + pid] = make_float4(o[4*qq+0], o[4*qq+1], o[4*qq+2], o[4*qq+3]);

    __syncthreads();
    TileSpan ts = tile_span(X, Y, Z);
    #pragma unroll
    for (int ez = 0; ez < 2; ++ez) {
        if (ez && ts.tzb == ts.tza) continue;
        #pragma unroll
        for (int ey = 0; ey < 2; ++ey) {
            if (ey && ts.tyb == ts.tya) continue;
            #pragma unroll
            for (int ex = 0; ex < 2; ++ex) {
                if (ex && ts.txb == ts.txa) continue;
                int tt = ((ts.tza + ez) * TPA + (ts.tya + ey)) * TPA + (ts.txa + ex);
                atomicAdd(&lcnt[tt], 1u);
            }
        }
    }
    __syncthreads();
    for (int i = tid; i < NTILES; i += 256)
        if (lcnt[i]) atomicAdd(&counts[i], lcnt[i]);
}

// ============================================================================
// K2 v2 (r15, unchanged): parallel shuffle prefix-sums + heavy-first order.
// ============================================================================
__global__ __launch_bounds__(256) void k2_scan(
    const unsigned* __restrict__ counts,
    unsigned* __restrict__ offsets, unsigned* __restrict__ alloc,
    unsigned* __restrict__ order)
{
    __shared__ unsigned wsum[4], wbase[4];
    __shared__ unsigned bwsum[4], bwbase[4];
    __shared__ unsigned bh[256];
    __shared__ unsigned bb[256];
    int tid = threadIdx.x, lane = tid & 63, wv = tid >> 6;
    unsigned base = tid * 16;
    unsigned loc[16];
    unsigned ssum = 0;
    #pragma unroll
    for (int i = 0; i < 16; ++i) { loc[i] = counts[base + i]; ssum += loc[i]; }
    bh[tid] = 0;

    unsigned x = ssum;
    #pragma unroll
    for (int d = 1; d < 64; d <<= 1) {
        unsigned v = __shfl_up(x, d);
        if (lane >= d) x += v;
    }
    if (lane == 63) wsum[wv] = x;
    __syncthreads();
    if (tid == 0) { unsigned r = 0; for (int ww = 0; ww < 4; ++ww) { wbase[ww] = r; r += wsum[ww]; } }
    __syncthreads();
    unsigned run = wbase[wv] + x - ssum;
    #pragma unroll
    for (int i = 0; i < 16; ++i) {
        unsigned v = loc[i];
        offsets[base + i] = run;
        alloc[base + i]   = run;
        run += v;
        atomicAdd(&bh[min(v >> 4, 255u)], 1u);
    }
    __syncthreads();

    unsigned hv = bh[255 - tid];
    unsigned y = hv;
    #pragma unroll
    for (int d = 1; d < 64; d <<= 1) {
        unsigned v = __shfl_up(y, d);
        if (lane >= d) y += v;
    }
    if (lane == 63) bwsum[wv] = y;
    __syncthreads();
    if (tid == 0) { unsigned r = 0; for (int ww = 0; ww < 4; ++ww) { bwbase[ww] = r; r += bwsum[ww]; } }
    __syncthreads();
    bb[255 - tid] = bwbase[wv] + y - hv;
    __syncthreads();
    #pragma unroll
    for (int i = 0; i < 16; ++i) {
        unsigned v = loc[i];
        unsigned slot = atomicAdd(&bb[min(v >> 4, 255u)], 1u);
        order[slot] = base + i;
    }
}

// ============================================================================
// K3: scatter point indices into per-tile segments (unchanged).
// ============================================================================
__global__ __launch_bounds__(256) void k3_scatter(
    const float4* __restrict__ pf, unsigned* __restrict__ alloc,
    unsigned* __restrict__ entries)
{
    __shared__ unsigned lcnt[NTILES];
    __shared__ unsigned lbase[NTILES];
    for (int i = threadIdx.x; i < NTILES; i += 256) lcnt[i] = 0;
    __syncthreads();

    int pid = blockIdx.x * 256 + threadIdx.x;
    float4 f = pf[pid];
    unsigned key = __float_as_uint(f.w);
    int X = (int)(key & 511u) - 256;
    int Y = (int)((key >> 9) & 511u) - 256;
    int Z = (int)((key >> 18) & 511u) - 256;
    TileSpan ts = tile_span(X, Y, Z);

    unsigned rnk[2][2][2];
    #pragma unroll
    for (int ez = 0; ez < 2; ++ez) {
        bool okz = (ez == 0) || (ts.tzb > ts.tza);
        #pragma unroll
        for (int ey = 0; ey < 2; ++ey) {
            bool oky = (ey == 0) || (ts.tyb > ts.tya);
            #pragma unroll
            for (int ex = 0; ex < 2; ++ex) {
                bool okx = (ex == 0) || (ts.txb > ts.txa);
                if (okz && oky && okx) {
                    int tt = ((ts.tza + ez) * TPA + (ts.tya + ey)) * TPA + (ts.txa + ex);
                    rnk[ez][ey][ex] = atomicAdd(&lcnt[tt], 1u);
                }
            }
        }
    }
    __syncthreads();
    for (int i = threadIdx.x; i < NTILES; i += 256)
        if (lcnt[i]) lbase[i] = atomicAdd(&alloc[i], lcnt[i]);
    __syncthreads();
    #pragma unroll
    for (int ez = 0; ez < 2; ++ez) {
        bool okz = (ez == 0) || (ts.tzb > ts.tza);
        #pragma unroll
        for (int ey = 0; ey < 2; ++ey) {
            bool oky = (ey == 0) || (ts.tyb > ts.tya);
            #pragma unroll
            for (int ex = 0; ex < 2; ++ex) {
                bool okx = (ex == 0) || (ts.txb > ts.txa);
                if (okz && oky && okx) {
                    int tt = ((ts.tza + ez) * TPA + (ts.tya + ey)) * TPA + (ts.txa + ex);
                    entries[lbase[tt] + rnk[ez][ey][ex]] = (unsigned)pid;
                }
            }
        }
    }
}

// ============================================================================
// K4 v4: ballot hit lists (r15) + HOISTED sO loads. The 4 sO b128 broadcasts
// move OUT of the per-layer guards: dual-hit iterations (~40%) no longer load
// them twice, and the two 16-FMA blocks schedule back-to-back off the same
// registers. Everything else identical to r15.
// ============================================================================
__global__ __launch_bounds__(256) void k4_accum(
    const float4* __restrict__ pf, const float4* __restrict__ po,
    const unsigned* __restrict__ entries, const unsigned* __restrict__ offsets,
    const unsigned* __restrict__ alloc, const unsigned* __restrict__ order,
    float* __restrict__ out)
{
    __shared__ __attribute__((aligned(16))) float4 sA[CHUNK];   // fx,fy,fz, cx0|cx1|cy0|cy1
    __shared__ __attribute__((aligned(16))) int    sZ[CHUNK];   // st0|st1<<8 (255=out)
    __shared__ __attribute__((aligned(16))) float4 sO[4*CHUNK]; // o[16] planar [q][entry]
    __shared__ unsigned long long sMask[4][4];                  // [target wave][group]

    int t  = order[blockIdx.x];      // heavy tiles scheduled first
    int tx = t & (TPA-1), ty = (t >> 4) & (TPA-1), tz = t >> 8;
    int ox = tx * TW, oy = ty * TW, oz = tz * TW;

    int tid  = threadIdx.x;
    int lane = tid & 63;
    int w    = tid >> 6;             // wave id, owns z-layers {2w, 2w+1}
    int vxa  = ox + (lane & 7);
    int vya  = oy + (lane >> 3);
    int l0   = 2*w, l1 = 2*w + 1;

    float accA[C_OUT], accB[C_OUT];
    #pragma unroll
    for (int c = 0; c < C_OUT; ++c) { accA[c] = 0.0f; accB[c] = 0.0f; }

    unsigned e0 = offsets[t], e1 = alloc[t];
    for (unsigned base = e0; base < e1; base += CHUNK) {
        int n = min((unsigned)CHUNK, e1 - base);
        int st0 = 255, st1 = 255;
        if (tid < n) {
            unsigned p = entries[base + tid];
            float4 f = pf[p];
            unsigned key = __float_as_uint(f.w);
            int X = (int)(key & 511u) - 256;
            int Y = (int)((key >> 9) & 511u) - 256;
            int Z = (int)((key >> 18) & 511u) - 256;
            int cx0 = clampi(X, GW-1),  cx1 = clampi(X+1, GW-1);
            int cy0 = clampi(Y, GH-1),  cy1 = clampi(Y+1, GH-1);
            int cz0 = clampi(Z, GD-1),  cz1 = clampi(Z+1, GD-1);
            unsigned pk = (unsigned)cx0 | ((unsigned)cx1 << 8)
                        | ((unsigned)cy0 << 16) | ((unsigned)cy1 << 24);
            st0 = ((unsigned)(cz0 - oz) < 8u) ? (cz0 - oz) : 255;
            st1 = ((unsigned)(cz1 - oz) < 8u) ? (cz1 - oz) : 255;
            sA[tid] = make_float4(f.x, f.y, f.z, __uint_as_float(pk));
            sZ[tid] = st0 | (st1 << 8);
            #pragma unroll
            for (int q = 0; q < 4; ++q)
                sO[q*CHUNK + tid] = po[(size_t)q * M_PTS + p];
        }
        int w0 = st0 >> 1, w1 = st1 >> 1;
        #pragma unroll
        for (int tw = 0; tw < 4; ++tw) {
            unsigned long long m = __ballot((w0 == tw) | (w1 == tw));
            if (lane == 0) sMask[tw][tid >> 6] = m;
        }
        __syncthreads();

        #pragma unroll
        for (int g = 0; g < 4; ++g) {
            unsigned long long m = sMask[w][g];      // wave-uniform
            while (m) {
                int j = (g << 6) + (int)__builtin_ctzll(m);
                m &= m - 1;
                float4 a = sA[j];
                int zz = sZ[j];
                int s0 = zz & 255, s1 = (zz >> 8) & 255;
                unsigned pk = __float_as_uint(a.w);
                int cx0 = (int)(pk & 255u),         cx1 = (int)((pk >> 8) & 255u);
                int cy0 = (int)((pk >> 16) & 255u), cy1 = (int)(pk >> 24);

                float wx = ((vxa == cx0) ? 1.0f - a.x : 0.0f)
                         + ((vxa == cx1) ? a.x        : 0.0f);
                float wy = ((vya == cy0) ? 1.0f - a.y : 0.0f)
                         + ((vya == cy1) ? a.y        : 0.0f);
                float wxy = wx * wy;

                // hoisted: load once, share across both layer guards
                float4 ov0 = sO[j];
                float4 ov1 = sO[CHUNK + j];
                float4 ov2 = sO[2*CHUNK + j];
                float4 ov3 = sO[3*CHUNK + j];

                bool hitA = (s0 == l0) | (s1 == l0);   // wave-uniform
                if (hitA) {
                    float wzA = ((s0 == l0) ? 1.0f - a.z : 0.0f)
                              + ((s1 == l0) ? a.z        : 0.0f);
                    float wA = wxy * wzA;
                    accA[0]  = fmaf(wA, ov0.x, accA[0]);  accA[1]  = fmaf(wA, ov0.y, accA[1]);
                    accA[2]  = fmaf(wA, ov0.z, accA[2]);  accA[3]  = fmaf(wA, ov0.w, accA[3]);
                    accA[4]  = fmaf(wA, ov1.x, accA[4]);  accA[5]  = fmaf(wA, ov1.y, accA[5]);
                    accA[6]  = fmaf(wA, ov1.z, accA[6]);  accA[7]  = fmaf(wA, ov1.w, accA[7]);
                    accA[8]  = fmaf(wA, ov2.x, accA[8]);  accA[9]  = fmaf(wA, ov2.y, accA[9]);
                    accA[10] = fmaf(wA, ov2.z, accA[10]); accA[11] = fmaf(wA, ov2.w, accA[11]);
                    accA[12] = fmaf(wA, ov3.x, accA[12]); accA[13] = fmaf(wA, ov3.y, accA[13]);
                    accA[14] = fmaf(wA, ov3.z, accA[14]); accA[15] = fmaf(wA, ov3.w, accA[15]);
                }
                bool hitB = (s0 == l1) | (s1 == l1);   // wave-uniform
                if (hitB) {
                    float wzB = ((s0 == l1) ? 1.0f - a.z : 0.0f)
                              + ((s1 == l1) ? a.z        : 0.0f);
                    float wB = wxy * wzB;
                    accB[0]  = fmaf(wB, ov0.x, accB[0]);  accB[1]  = fmaf(wB, ov0.y, accB[1]);
                    accB[2]  = fmaf(wB, ov0.z, accB[2]);  accB[3]  = fmaf(wB, ov0.w, accB[3]);
                    accB[4]  = fmaf(wB, ov1.x, accB[4]);  accB[5]  = fmaf(wB, ov1.y, accB[5]);
                    accB[6]  = fmaf(wB, ov1.z, accB[6]);  accB[7]  = fmaf(wB, ov1.w, accB[7]);
                    accB[8]  = fmaf(wB, ov2.x, accB[8]);  accB[9]  = fmaf(wB, ov2.y, accB[9]);
                    accB[10] = fmaf(wB, ov2.z, accB[10]); accB[11] = fmaf(wB, ov2.w, accB[11]);
                    accB[12] = fmaf(wB, ov3.x, accB[12]); accB[13] = fmaf(wB, ov3.y, accB[13]);
                    accB[14] = fmaf(wB, ov3.z, accB[14]); accB[15] = fmaf(wB, ov3.w, accB[15]);
                }
            }
        }
        __syncthreads();
    }

    // ---- dense register writeback (full coverage -> no memset needed) ----
    size_t baseA = ((((size_t)(oz + l0)) * GH + vya) * GW + vxa) * C_OUT;
    size_t baseB = ((((size_t)(oz + l1)) * GH + vya) * GW + vxa) * C_OUT;
    #pragma unroll
    for (int q = 0; q < 4; ++q) {
        *(float4*)(out + baseA + 4*q) = make_float4(accA[4*q+0], accA[4*q+1], accA[4*q+2], accA[4*q+3]);
        *(float4*)(out + baseB + 4*q) = make_float4(accB[4*q+0], accB[4*q+1], accB[4*q+2], accB[4*q+3]);
    }
}

// ============================================================================
// Fallback (round-3 fused kernel) if workspace is too small.
// ============================================================================
#define SEGS   8
#define SEGLEN (NSAMP / SEGS)
#define NTHREADS (N_RAYS * SEGS)

__global__ __launch_bounds__(256, 2) void splat_seg_kernel(
    const float* __restrict__ origins, const float* __restrict__ dirs,
    const float* __restrict__ nearv,   const float* __restrict__ farv,
    const float* __restrict__ enc,     const int*   __restrict__ gidx,
    const float* __restrict__ grid,    const float* __restrict__ W0,
    const float* __restrict__ b0,      const float* __restrict__ W1,
    const float* __restrict__ b1,      float* __restrict__ out)
{
    int tid = blockIdx.x * blockDim.x + threadIdx.x;
    if (tid >= NTHREADS) return;
    int ray = tid / SEGS;
    int seg = tid - ray * SEGS;
    float nr = nearv[ray], fr = farv[ray];
    float ox = origins[3*ray+0], oy = origins[3*ray+1], oz = origins[3*ray+2];
    float rdx = dirs[3*ray+0],   rdy = dirs[3*ray+1],   rdz = dirs[3*ray+2];
    int   b  = gidx[ray];
    float accv[8][C_OUT];
    #pragma unroll
    for (int sl = 0; sl < 8; ++sl)
        #pragma unroll
        for (int c = 0; c < C_OUT; ++c) accv[sl][c] = 0.0f;
    int Xp = 0, Yp = 0, Zp = 0;
    #pragma unroll 1
    for (int k = 0; k < SEGLEN; ++k) {
        int s = seg * SEGLEN + k;
        float t  = nr + (fr - nr) * ((float)s * (1.0f / (NSAMP - 1)));
        float px = fmaf(t, rdx, ox);
        float py = fmaf(t, rdy, oy);
        float pz = fmaf(t, rdz, oz);
        float cx = ((px + 1.0f) * (float)GW - 1.0f) * 0.5f;
        float cy = ((py + 1.0f) * (float)GH - 1.0f) * 0.5f;
        float cz = ((pz + 1.0f) * (float)GD - 1.0f) * 0.5f;
        float fxf = floorf(cx), fyf = floorf(cy), fzf = floorf(cz);
        float fx = cx - fxf, fy = cy - fyf, fz = cz - fzf;
        int X = (int)fxf, Y = (int)fyf, Z = (int)fzf;
        if (k == 0) { Xp = X; Yp = Y; Zp = Z; }
        else if (X != Xp || Y != Yp || Z != Zp) {
            bool fXm[2], fYm[2], fZm[2];
            int  vx[2], vy[2], vz[2];
            #pragma unroll
            for (int p = 0; p < 2; ++p) {
                int xo = Xp + ((Xp ^ p) & 1), xn = X + ((X ^ p) & 1);
                fXm[p] = (xo != xn);  vx[p] = clampi(xo, GW-1);
                int yo = Yp + ((Yp ^ p) & 1), yn = Y + ((Y ^ p) & 1);
                fYm[p] = (yo != yn);  vy[p] = clampi(yo, GH-1);
                int zo = Zp + ((Zp ^ p) & 1), zn = Z + ((Z ^ p) & 1);
                fZm[p] = (zo != zn);  vz[p] = clampi(zo, GD-1);
            }
            #pragma unroll
            for (int pxi = 0; pxi < 2; ++pxi)
            #pragma unroll
            for (int pyi = 0; pyi < 2; ++pyi)
            #pragma unroll
            for (int pzi = 0; pzi < 2; ++pzi) {
                const int sl = pxi*4 + pyi*2 + pzi;
                if (fXm[pxi] | fYm[pyi] | fZm[pzi]) {
                    size_t flat = ((((size_t)b * GD + vz[pzi]) * GH + vy[pyi]) * GW + vx[pxi]) * C_OUT;
                    float* op = out + flat;
                    #pragma unroll
                    for (int c = 0; c < C_OUT; ++c) { atomicAdd(op + c, accv[sl][c]); accv[sl][c] = 0.0f; }
                }
            }
            Xp = X; Yp = Y; Zp = Z;
        }
        float feat[C_IN];
        {
            const float4* e4 = (const float4*)(enc + (size_t)ray * C_IN);
            #pragma unroll
            for (int q = 0; q < C_IN/4; ++q) {
                float4 v = e4[q];
                feat[4*q+0] = v.x; feat[4*q+1] = v.y; feat[4*q+2] = v.z; feat[4*q+3] = v.w;
            }
        }
        int gx[2] = { clampi(X, GW-1), clampi(X+1, GW-1) };
        int gy[2] = { clampi(Y, GH-1), clampi(Y+1, GH-1) };
        int gz[2] = { clampi(Z, GD-1), clampi(Z+1, GD-1) };
        float wxa[2] = { 1.0f - fx, fx };
        float wya[2] = { 1.0f - fy, fy };
        float wza[2] = { 1.0f - fz, fz };
        #pragma unroll
        for (int dz = 0; dz < 2; ++dz)
        #pragma unroll
        for (int dy = 0; dy < 2; ++dy)
        #pragma unroll
        for (int dx = 0; dx < 2; ++dx) {
            float w = wza[dz] * wya[dy] * wxa[dx];
            size_t flat = ((((size_t)b * GD + gz[dz]) * GH + gy[dy]) * GW + gx[dx]) * C_IN;
            const float4* g4 = (const float4*)(grid + flat);
            #pragma unroll
            for (int q = 0; q < C_IN/4; ++q) {
                float4 v = g4[q];
                feat[4*q+0] = fmaf(w, v.x, feat[4*q+0]);
                feat[4*q+1] = fmaf(w, v.y, feat[4*q+1]);
                feat[4*q+2] = fmaf(w, v.z, feat[4*q+2]);
                feat[4*q+3] = fmaf(w, v.w, feat[4*q+3]);
            }
        }
        float h[C_HID];
        #pragma unroll
        for (int j = 0; j < C_HID; ++j) h[j] = b0[j];
        #pragma unroll
        for (int i = 0; i < C_IN; ++i) {
            float xi = feat[i];
            #pragma unroll
            for (int j = 0; j < C_HID; ++j) h[j] = fmaf(xi, W0[i*C_HID + j], h[j]);
        }
        #pragma unroll
        for (int j = 0; j < C_HID; ++j) h[j] = fmaxf(h[j], 0.0f);
        float o[C_OUT];
        #pragma unroll
        for (int j = 0; j < C_OUT; ++j) o[j] = b1[j];
        #pragma unroll
        for (int i = 0; i < C_HID; ++i) {
            float hi = h[i];
            #pragma unroll
            for (int j = 0; j < C_OUT; ++j) o[j] = fmaf(hi, W1[i*C_OUT + j], o[j]);
        }
        float wxs[2], wys[2], wzs[2];
        #pragma unroll
        for (int p = 0; p < 2; ++p) {
            wxs[p] = ((X & 1) == p) ? (1.0f - fx) : fx;
            wys[p] = ((Y & 1) == p) ? (1.0f - fy) : fy;
            wzs[p] = ((Z & 1) == p) ? (1.0f - fz) : fz;
        }
        #pragma unroll
        for (int pxi = 0; pxi < 2; ++pxi)
        #pragma unroll
        for (int pyi = 0; pyi < 2; ++pyi)
        #pragma unroll
        for (int pzi = 0; pzi < 2; ++pzi) {
            const int sl = pxi*4 + pyi*2 + pzi;
            float w = wxs[pxi] * wys[pyi] * wzs[pzi];
            #pragma unroll
            for (int c = 0; c < C_OUT; ++c) accv[sl][c] = fmaf(w, o[c], accv[sl][c]);
        }
    }
    #pragma unroll
    for (int pxi = 0; pxi < 2; ++pxi)
    #pragma unroll
    for (int pyi = 0; pyi < 2; ++pyi)
    #pragma unroll
    for (int pzi = 0; pzi < 2; ++pzi) {
        const int sl = pxi*4 + pyi*2 + pzi;
        int vx = clampi(Xp + ((Xp ^ pxi) & 1), GW-1);
        int vy = clampi(Yp + ((Yp ^ pyi) & 1), GH-1);
        int vz = clampi(Zp + ((Zp ^ pzi) & 1), GD-1);
        size_t flat = ((((size_t)b * GD + vz) * GH + vy) * GW + vx) * C_OUT;
        float* op = out + flat;
        #pragma unroll
        for (int c = 0; c < C_OUT; ++c) atomicAdd(op + c, accv[sl][c]);
    }
}

// ============================================================================
extern "C" void kernel_launch(void* const* d_in, const int* in_sizes, int n_in,
                              void* d_out, int out_size, void* d_ws, size_t ws_size,
                              hipStream_t stream) {
    const float* origins = (const float*)d_in[0];
    const float* dirs    = (const float*)d_in[1];
    const float* nearv   = (const float*)d_in[2];
    const float* farv    = (const float*)d_in[3];
    const float* enc     = (const float*)d_in[4];
    const int*   gidx    = (const int*)  d_in[5];
    const float* grid    = (const float*)d_in[6];
    const float* W0      = (const float*)d_in[7];
    const float* b0      = (const float*)d_in[8];
    const float* W1      = (const float*)d_in[9];
    const float* b1      = (const float*)d_in[10];
    float* out = (float*)d_out;

    const size_t PF_B = (size_t)M_PTS * 16;         // 25,165,824
    const size_t PO_B = (size_t)M_PTS * 64;         // 100,663,296
    const size_t EN_B = (size_t)M_PTS * 8 * 4;      // 50,331,648 (hard bound)
    const size_t CT_B = (size_t)NTILES * 4;
    const size_t NEED = PF_B + PO_B + EN_B + 4 * CT_B;

    if (ws_size < NEED) {
        // fallback: fused register-merged scatter (round-3 path)
        hipMemsetAsync(out, 0, (size_t)out_size * sizeof(float), stream);
        splat_seg_kernel<<<NTHREADS/256, 256, 0, stream>>>(
            origins, dirs, nearv, farv, enc, gidx, grid, W0, b0, W1, b1, out);
        return;
    }

    char* w = (char*)d_ws;
    float4*   pf      = (float4*)   w;              w += PF_B;
    float4*   po      = (float4*)   w;              w += PO_B;
    unsigned* entries = (unsigned*) w;              w += EN_B;
    unsigned* counts  = (unsigned*) w;              w += CT_B;
    unsigned* offsets = (unsigned*) w;              w += CT_B;
    unsigned* alloc   = (unsigned*) w;              w += CT_B;
    unsigned* order   = (unsigned*) w;              w += CT_B;

    hipMemsetAsync(counts, 0, CT_B, stream);
    k1_point<<<M_PTS/256, 256, 0, stream>>>(origins, dirs, nearv, farv, enc, gidx,
                                            grid, W0, b0, W1, b1, pf, po, counts);
    k2_scan<<<1, 256, 0, stream>>>(counts, offsets, alloc, order);
    k3_scatter<<<M_PTS/256, 256, 0, stream>>>(pf, alloc, entries);
    k4_accum<<<NTILES, 256, 0, stream>>>(pf, po, entries, offsets, alloc, order, out);
    // K4 writes every output voxel densely -> no output memset needed.
}